// Round 1
// baseline (478.297 us; speedup 1.0000x reference)
//
#include <hip/hip_runtime.h>

#define B_ 4
#define N_ 2048
#define K_ 32
#define CIN_ 16
#define COUT_ 32
#define H_ 32
#define R_ (B_*N_*K_)      // 262144 rows through the weight-net
#define EPS_ 1e-5f
#define QPB 4              // queries (waves) per block in knn
#define LISTCAP 384

// identical fma association everywhere so self-distance is exactly 0 and
// recomputed h1/h2 match the stats-pass values bit-for-bit
__device__ __forceinline__ float dot3f(float ax,float ay,float az,float bx,float by,float bz){
    return fmaf(az,bz, fmaf(ay,by, ax*bx));
}
__device__ __forceinline__ unsigned long long umin64(unsigned long long a, unsigned long long b){
    return a < b ? a : b;
}
__device__ __forceinline__ unsigned int flip_f32(float d){
    unsigned int u = __float_as_uint(d);
    return u ^ ((unsigned int)(((int)u) >> 31) | 0x80000000u);  // total order: ascending float -> ascending uint
}

// ---------------- KNN: exact top-32 smallest dist, tie -> smallest index ----------------
__global__ __launch_bounds__(256) void k_knn(const float* __restrict__ xyz, int* __restrict__ idx_out){
    __shared__ float xs[N_*3];            // 24 KB
    __shared__ float sqs[N_];             // 8 KB
    __shared__ unsigned int hist[QPB][256];
    __shared__ unsigned long long lst[QPB][LISTCAP];
    __shared__ unsigned int cnt[QPB];

    const int tid  = threadIdx.x;
    const int w    = tid >> 6;
    const int lane = tid & 63;
    const int b    = blockIdx.x / (N_/QPB);
    const int q    = (blockIdx.x % (N_/QPB)) * QPB + w;   // query index within batch

    const float* xb = xyz + (size_t)b * N_ * 3;
    for (int i = tid; i < N_*3; i += 256) xs[i] = xb[i];
    __syncthreads();
    for (int i = tid; i < N_; i += 256){
        float x = xs[3*i], y = xs[3*i+1], z = xs[3*i+2];
        sqs[i] = dot3f(x,y,z,x,y,z);
    }
    for (int i = lane; i < 256; i += 64) hist[w][i] = 0;
    if (lane == 0) cnt[w] = 0;
    __syncthreads();

    const float qx = xs[3*q], qy = xs[3*q+1], qz = xs[3*q+2];
    const float sqq = sqs[q];

    // pass 1: histogram of top-8-bits of order-flipped distance
    #pragma unroll 4
    for (int j = 0; j < 32; ++j){
        int c = j*64 + lane;
        float d = fmaf(-2.0f, dot3f(qx,qy,qz, xs[3*c], xs[3*c+1], xs[3*c+2]), sqq) + sqs[c];
        atomicAdd(&hist[w][flip_f32(d) >> 24], 1u);
    }
    __syncthreads();

    // find smallest bucket Bsel with cumulative count >= K_
    unsigned int g0=hist[w][4*lane], g1=hist[w][4*lane+1], g2=hist[w][4*lane+2], g3=hist[w][4*lane+3];
    unsigned int gs = g0+g1+g2+g3;
    unsigned int cum = gs;
    #pragma unroll
    for (int off=1; off<64; off<<=1){
        unsigned int v = __shfl_up(cum, off);
        if (lane >= off) cum += v;
    }
    unsigned long long bal = __ballot(cum >= (unsigned)K_);
    int L = __ffsll(bal) - 1;
    unsigned int run = __shfl(cum, L) - __shfl(gs, L);   // exclusive prefix before group L
    unsigned int h0=hist[w][4*L], h1=hist[w][4*L+1], h2=hist[w][4*L+2];
    int Bsel = 4*L+3;
    if      (run + h0 >= (unsigned)K_)           Bsel = 4*L;
    else if (run + h0 + h1 >= (unsigned)K_)      Bsel = 4*L+1;
    else if (run + h0 + h1 + h2 >= (unsigned)K_) Bsel = 4*L+2;

    // pass 2: collect all candidates with bucket <= Bsel (>= 32 of them, ~60 typical)
    #pragma unroll 4
    for (int j = 0; j < 32; ++j){
        int c = j*64 + lane;
        float d = fmaf(-2.0f, dot3f(qx,qy,qz, xs[3*c], xs[3*c+1], xs[3*c+2]), sqq) + sqs[c];
        unsigned int f = flip_f32(d);
        if ((int)(f >> 24) <= Bsel){
            unsigned int pos = atomicAdd(&cnt[w], 1u);
            if (pos < LISTCAP) lst[w][pos] = ((unsigned long long)f << 32) | (unsigned int)c;
        }
    }
    __syncthreads();
    int m = (int)cnt[w]; if (m > LISTCAP) m = LISTCAP;

    int* outp = idx_out + ((size_t)b * N_ + q) * K_;
    for (int r = 0; r < K_; ++r){
        unsigned long long best = ~0ull;
        for (int i = lane; i < m; i += 64) best = umin64(best, lst[w][i]);
        #pragma unroll
        for (int off = 32; off; off >>= 1)
            best = umin64(best, (unsigned long long)__shfl_xor(best, off));
        for (int i = lane; i < m; i += 64) if (lst[w][i] == best) lst[w][i] = ~0ull;
        __threadfence_block();
        if (lane == 0) outp[r] = (int)(unsigned int)(best & 0xFFFFFFFFull);
    }
}

// ---------------- shared MLP helpers (identical codegen across kernels) ----------------
__device__ __forceinline__ void compute_h1(const float* __restrict__ xyz, const int* __restrict__ idx, int r,
                                           const float* W1s /*96*/, const float* b1s /*32*/, float* h1){
    int b = r >> 16;            // N_*K_ = 65536
    int n = (r >> 5) & (N_-1);
    int id = idx[r];
    const float* pc = xyz + ((size_t)b*N_ + n)*3;
    const float* pn = xyz + ((size_t)b*N_ + id)*3;
    float rx = pn[0]-pc[0], ry = pn[1]-pc[1], rz = pn[2]-pc[2];
    #pragma unroll
    for (int j = 0; j < H_; ++j){
        float a = fmaf(rx, W1s[j], fmaf(ry, W1s[H_+j], fmaf(rz, W1s[2*H_+j], b1s[j])));
        h1[j] = fmaxf(a, 0.0f);
    }
}

__device__ __forceinline__ void mlp12(const float* __restrict__ xyz, const int* __restrict__ idx, int r,
                                      const float* W1s, const float* b1s, const float* A1s /*a1|bb1*/,
                                      const float* W2s /*1024*/, const float* b2s /*32*/, float* h2){
    float h1[H_];
    compute_h1(xyz, idx, r, W1s, b1s, h1);
    #pragma unroll
    for (int j = 0; j < H_; ++j) h1[j] = fmaf(A1s[j], h1[j], A1s[H_+j]);
    #pragma unroll
    for (int j = 0; j < H_; ++j) h2[j] = b2s[j];
    #pragma unroll 4
    for (int hh = 0; hh < H_; ++hh){
        float c = h1[hh];
        #pragma unroll
        for (int j = 0; j < H_; ++j) h2[j] = fmaf(c, W2s[hh*H_+j], h2[j]);
    }
    #pragma unroll
    for (int j = 0; j < H_; ++j) h2[j] = fmaxf(h2[j], 0.0f);
}

// block-level per-channel sum/sumsq -> 64 global atomics per block. tile stride 33 kills bank conflicts.
#define TSTRIDE 33
__device__ __forceinline__ void block_stats(float* tile /*256*33*/, const float* h,
                                            float* __restrict__ gsum, float* __restrict__ gsq){
    int tid = threadIdx.x;
    #pragma unroll
    for (int j = 0; j < H_; ++j) tile[tid*TSTRIDE + j] = h[j];
    __syncthreads();
    int cho = tid & 31, chunk = tid >> 5;
    float s = 0.f, q = 0.f;
    #pragma unroll
    for (int rr = 0; rr < 32; ++rr){
        float v = tile[(chunk*32 + rr)*TSTRIDE + cho];
        s += v; q = fmaf(v, v, q);
    }
    __syncthreads();
    tile[tid] = s; tile[256 + tid] = q;   // [chunk*32+cho] == tid
    __syncthreads();
    if (tid < 32){
        float ss = 0.f, qq = 0.f;
        #pragma unroll
        for (int g = 0; g < 8; ++g){ ss += tile[g*32 + tid]; qq += tile[256 + g*32 + tid]; }
        atomicAdd(&gsum[tid], ss);
        atomicAdd(&gsq[tid], qq);
    }
}

__global__ __launch_bounds__(256) void k_h1stats(const float* __restrict__ xyz, const int* __restrict__ idx,
                                                 const float* __restrict__ W1, const float* __restrict__ b1,
                                                 float* gsum, float* gsq){
    __shared__ float W1s[4*H_];
    __shared__ float tile[256*TSTRIDE];
    int tid = threadIdx.x;
    if (tid < 4*H_) W1s[tid] = (tid < 3*H_) ? W1[tid] : b1[tid - 3*H_];
    __syncthreads();
    int r = blockIdx.x*256 + tid;
    float h1[H_];
    compute_h1(xyz, idx, r, W1s, W1s + 3*H_, h1);
    block_stats(tile, h1, gsum, gsq);
}

__global__ __launch_bounds__(256) void k_h2stats(const float* __restrict__ xyz, const int* __restrict__ idx,
                                                 const float* __restrict__ W1, const float* __restrict__ b1,
                                                 const float* __restrict__ a1, const float* __restrict__ bb1,
                                                 const float* __restrict__ W2, const float* __restrict__ b2,
                                                 float* gsum, float* gsq){
    __shared__ float W1s[4*H_];
    __shared__ float A1s[2*H_];
    __shared__ float W2s[H_*H_];
    __shared__ float b2s[H_];
    __shared__ float tile[256*TSTRIDE];
    int tid = threadIdx.x;
    if (tid < 4*H_) W1s[tid] = (tid < 3*H_) ? W1[tid] : b1[tid - 3*H_];
    if (tid >= 128 && tid < 192) A1s[tid-128] = (tid < 160) ? a1[tid-128] : bb1[tid-160];
    for (int i = tid; i < H_*H_; i += 256) W2s[i] = W2[i];
    if (tid < H_) b2s[tid] = b2[tid];
    __syncthreads();
    int r = blockIdx.x*256 + tid;
    float h2[H_];
    mlp12(xyz, idx, r, W1s, W1s + 3*H_, A1s, W2s, b2s, h2);
    block_stats(tile, h2, gsum, gsq);
}

__global__ void k_fin(const float* gsum, const float* gsq, const float* __restrict__ g,
                      const float* __restrict__ be, float invn, float* a, float* bb){
    int j = threadIdx.x;
    if (j < 32){
        float m = gsum[j] * invn;
        float v = gsq[j] * invn - m*m;
        float aj = g[j] / sqrtf(v + EPS_);
        a[j] = aj;
        bb[j] = fmaf(-aj, m, be[j]);
    }
}

// ---------------- main fused stage: recompute h2 -> BN2 -> (h2n@W3+b3) . pts -> max over k ----------------
__global__ __launch_bounds__(256,2) void k_out(const float* __restrict__ xyz, const float* __restrict__ points,
                                               const int* __restrict__ idx,
                                               const float* __restrict__ W1, const float* __restrict__ b1,
                                               const float* __restrict__ a1, const float* __restrict__ bb1,
                                               const float* __restrict__ W2, const float* __restrict__ b2,
                                               const float* __restrict__ a2, const float* __restrict__ bb2,
                                               const float* __restrict__ W3, const float* __restrict__ b3,
                                               float* __restrict__ out_pre, float* gsum, float* gsq){
    __shared__ float W3s[H_*CIN_*COUT_];   // 64 KB
    __shared__ float b3s[CIN_*COUT_];      // 2 KB
    __shared__ float W2s[H_*H_];           // 4 KB
    __shared__ float b2s[H_];
    __shared__ float W1s[4*H_];
    __shared__ float A1s[2*H_];
    __shared__ float A2s[2*H_];
    __shared__ float red[8*COUT_];
    int tid = threadIdx.x;
    for (int i = tid; i < H_*CIN_*COUT_; i += 256) W3s[i] = W3[i];
    for (int i = tid; i < CIN_*COUT_; i += 256) b3s[i] = b3[i];
    for (int i = tid; i < H_*H_; i += 256) W2s[i] = W2[i];
    if (tid < 4*H_) W1s[tid] = (tid < 3*H_) ? W1[tid] : b1[tid - 3*H_];
    if (tid >= 128 && tid < 192) A1s[tid-128] = (tid < 160) ? a1[tid-128] : bb1[tid-160];
    if (tid >= 192 && tid < 256) A2s[tid-192] = (tid < 224) ? a2[tid-192] : bb2[tid-224];
    if (tid < H_) b2s[tid] = b2[tid];
    __syncthreads();

    int r = blockIdx.x*256 + tid;
    int b = r >> 16;
    int id = idx[r];

    float h2n[H_];
    mlp12(xyz, idx, r, W1s, W1s + 3*H_, A1s, W2s, b2s, h2n);
    #pragma unroll
    for (int h = 0; h < H_; ++h) h2n[h] = fmaf(A2s[h], h2n[h], A2s[H_+h]);

    float gp[CIN_];
    const float4* pp = (const float4*)(points + ((size_t)b*N_ + id)*CIN_);
    #pragma unroll
    for (int c4 = 0; c4 < CIN_/4; ++c4){
        float4 v = pp[c4];
        gp[4*c4] = v.x; gp[4*c4+1] = v.y; gp[4*c4+2] = v.z; gp[4*c4+3] = v.w;
    }

    float4 t4[COUT_/4];
    #pragma unroll
    for (int i = 0; i < COUT_/4; ++i) t4[i] = make_float4(0.f,0.f,0.f,0.f);

    for (int c = 0; c < CIN_; ++c){
        const float gc = gp[c];
        const float4* b3v = (const float4*)(b3s + c*COUT_);
        #pragma unroll
        for (int i = 0; i < COUT_/4; ++i){
            float4 w4 = b3v[i];
            #pragma unroll 8
            for (int h = 0; h < H_; ++h){
                float4 wv = ((const float4*)(W3s + h*(CIN_*COUT_) + c*COUT_))[i];
                float hv = h2n[h];
                w4.x = fmaf(hv, wv.x, w4.x);
                w4.y = fmaf(hv, wv.y, w4.y);
                w4.z = fmaf(hv, wv.z, w4.z);
                w4.w = fmaf(hv, wv.w, w4.w);
            }
            t4[i].x = fmaf(gc, w4.x, t4[i].x);
            t4[i].y = fmaf(gc, w4.y, t4[i].y);
            t4[i].z = fmaf(gc, w4.z, t4[i].z);
            t4[i].w = fmaf(gc, w4.w, t4[i].w);
        }
    }

    // max over k: 32 consecutive lanes share one (b,n); xor-butterfly gives all lanes the max
    #pragma unroll
    for (int i = 0; i < COUT_/4; ++i){
        #pragma unroll
        for (int off = 16; off; off >>= 1){
            t4[i].x = fmaxf(t4[i].x, __shfl_xor(t4[i].x, off));
            t4[i].y = fmaxf(t4[i].y, __shfl_xor(t4[i].y, off));
            t4[i].z = fmaxf(t4[i].z, __shfl_xor(t4[i].z, off));
            t4[i].w = fmaxf(t4[i].w, __shfl_xor(t4[i].w, off));
        }
    }

    if ((tid & 31) == 0){
        float4* op = (float4*)(out_pre + ((size_t)(r >> 5)) * COUT_);
        #pragma unroll
        for (int i = 0; i < COUT_/4; ++i) op[i] = t4[i];
        float* rp = red + (tid >> 5) * COUT_;
        #pragma unroll
        for (int i = 0; i < COUT_/4; ++i) ((float4*)rp)[i] = t4[i];
    }
    __syncthreads();
    if (tid < COUT_){
        float ss = 0.f, qq = 0.f;
        #pragma unroll
        for (int g = 0; g < 8; ++g){ float v = red[g*COUT_ + tid]; ss += v; qq = fmaf(v, v, qq); }
        atomicAdd(&gsum[tid], ss);
        atomicAdd(&gsq[tid], qq);
    }
}

__global__ __launch_bounds__(256) void k_bn(const float* __restrict__ out_pre, const float* __restrict__ a,
                                            const float* __restrict__ bb, float* __restrict__ out){
    int i = blockIdx.x*256 + threadIdx.x;
    int o = i & (COUT_-1);
    out[i] = fmaf(a[o], out_pre[i], bb[o]);
}

__global__ void k_init(float* st){
    int i = threadIdx.x;
    for (int j = i; j < 384; j += 256) st[j] = 0.f;
}

extern "C" void kernel_launch(void* const* d_in, const int* in_sizes, int n_in,
                              void* d_out, int out_size, void* d_ws, size_t ws_size,
                              hipStream_t stream){
    const float* xyz    = (const float*)d_in[0];
    const float* points = (const float*)d_in[1];
    const float* W1  = (const float*)d_in[2];
    const float* b1  = (const float*)d_in[3];
    const float* g1  = (const float*)d_in[4];
    const float* be1 = (const float*)d_in[5];
    const float* W2  = (const float*)d_in[6];
    const float* b2  = (const float*)d_in[7];
    const float* g2  = (const float*)d_in[8];
    const float* be2 = (const float*)d_in[9];
    const float* W3  = (const float*)d_in[10];
    const float* b3  = (const float*)d_in[11];
    const float* gbn = (const float*)d_in[12];
    const float* bbn = (const float*)d_in[13];
    float* out = (float*)d_out;

    // ws layout (floats): idx[R_] | out_pre[B_*N_*COUT_] | stats[384]  (~2.2 MB total)
    int*   idx     = (int*)d_ws;
    float* out_pre = (float*)d_ws + R_;
    float* st      = out_pre + (size_t)B_*N_*COUT_;
    float *s1=st, *q1=st+32, *s2=st+64, *q2=st+96, *s3=st+128, *q3=st+160;
    float *a1=st+192, *bb1=st+224, *a2=st+256, *bb2=st+288, *a3=st+320, *bb3=st+352;

    hipLaunchKernelGGL(k_init,    dim3(1),             dim3(256), 0, stream, st);
    hipLaunchKernelGGL(k_knn,     dim3(B_*(N_/QPB)),   dim3(256), 0, stream, xyz, idx);
    hipLaunchKernelGGL(k_h1stats, dim3(R_/256),        dim3(256), 0, stream, xyz, idx, W1, b1, s1, q1);
    hipLaunchKernelGGL(k_fin,     dim3(1),             dim3(64),  0, stream, s1, q1, g1, be1, 1.0f/(float)R_, a1, bb1);
    hipLaunchKernelGGL(k_h2stats, dim3(R_/256),        dim3(256), 0, stream, xyz, idx, W1, b1, a1, bb1, W2, b2, s2, q2);
    hipLaunchKernelGGL(k_fin,     dim3(1),             dim3(64),  0, stream, s2, q2, g2, be2, 1.0f/(float)R_, a2, bb2);
    hipLaunchKernelGGL(k_out,     dim3(R_/256),        dim3(256), 0, stream, xyz, points, idx, W1, b1, a1, bb1,
                       W2, b2, a2, bb2, W3, b3, out_pre, s3, q3);
    hipLaunchKernelGGL(k_fin,     dim3(1),             dim3(64),  0, stream, s3, q3, gbn, bbn, 1.0f/(float)(B_*N_), a3, bb3);
    hipLaunchKernelGGL(k_bn,      dim3(B_*N_*COUT_/256), dim3(256), 0, stream, out_pre, a3, bb3, out);
}

// Round 2
// 369.495 us; speedup vs baseline: 1.2945x; 1.2945x over previous
//
#include <hip/hip_runtime.h>

#define B_ 4
#define N_ 2048
#define K_ 32
#define CIN_ 16
#define COUT_ 32
#define H_ 32
#define R_ (B_*N_*K_)      // 262144 rows through the weight-net
#define EPS_ 1e-5f
#define QPB 4              // queries (waves) per block in knn
#define LISTCAP 384

typedef __attribute__((ext_vector_type(8))) short short8;
typedef __attribute__((ext_vector_type(4))) float f32x4;

// identical fma association everywhere so self-distance is exactly 0 and
// recomputed h1/h2 match the stats-pass values bit-for-bit
__device__ __forceinline__ float dot3f(float ax,float ay,float az,float bx,float by,float bz){
    return fmaf(az,bz, fmaf(ay,by, ax*bx));
}
__device__ __forceinline__ unsigned long long umin64(unsigned long long a, unsigned long long b){
    return a < b ? a : b;
}
__device__ __forceinline__ unsigned int flip_f32(float d){
    unsigned int u = __float_as_uint(d);
    return u ^ ((unsigned int)(((int)u) >> 31) | 0x80000000u);  // total order
}
__device__ __forceinline__ unsigned short f2bf_rne(float x){
    unsigned int u = __float_as_uint(x);
    unsigned int r = u + 0x7FFFu + ((u >> 16) & 1u);
    return (unsigned short)(r >> 16);
}

// ---------------- KNN: exact top-32 smallest dist, tie -> smallest index ----------------
__global__ __launch_bounds__(256) void k_knn(const float* __restrict__ xyz, int* __restrict__ idx_out){
    __shared__ float xs[N_*3];            // 24 KB
    __shared__ float sqs[N_];             // 8 KB
    __shared__ unsigned int hist[QPB][256];
    __shared__ unsigned long long lst[QPB][LISTCAP];
    __shared__ unsigned int cnt[QPB];

    const int tid  = threadIdx.x;
    const int w    = tid >> 6;
    const int lane = tid & 63;
    const int b    = blockIdx.x / (N_/QPB);
    const int q    = (blockIdx.x % (N_/QPB)) * QPB + w;   // query index within batch

    const float* xb = xyz + (size_t)b * N_ * 3;
    for (int i = tid; i < N_*3; i += 256) xs[i] = xb[i];
    __syncthreads();
    for (int i = tid; i < N_; i += 256){
        float x = xs[3*i], y = xs[3*i+1], z = xs[3*i+2];
        sqs[i] = dot3f(x,y,z,x,y,z);
    }
    for (int i = lane; i < 256; i += 64) hist[w][i] = 0;
    if (lane == 0) cnt[w] = 0;
    __syncthreads();

    const float qx = xs[3*q], qy = xs[3*q+1], qz = xs[3*q+2];
    const float sqq = sqs[q];

    // pass 1: histogram of top-8-bits of order-flipped distance
    #pragma unroll 4
    for (int j = 0; j < 32; ++j){
        int c = j*64 + lane;
        float d = fmaf(-2.0f, dot3f(qx,qy,qz, xs[3*c], xs[3*c+1], xs[3*c+2]), sqq) + sqs[c];
        atomicAdd(&hist[w][flip_f32(d) >> 24], 1u);
    }
    __syncthreads();

    // find smallest bucket Bsel with cumulative count >= K_
    unsigned int g0=hist[w][4*lane], g1=hist[w][4*lane+1], g2=hist[w][4*lane+2], g3=hist[w][4*lane+3];
    unsigned int gs = g0+g1+g2+g3;
    unsigned int cum = gs;
    #pragma unroll
    for (int off=1; off<64; off<<=1){
        unsigned int v = __shfl_up(cum, off);
        if (lane >= off) cum += v;
    }
    unsigned long long bal = __ballot(cum >= (unsigned)K_);
    int L = __ffsll(bal) - 1;
    unsigned int run = __shfl(cum, L) - __shfl(gs, L);   // exclusive prefix before group L
    unsigned int h0=hist[w][4*L], h1=hist[w][4*L+1], h2=hist[w][4*L+2];
    int Bsel = 4*L+3;
    if      (run + h0 >= (unsigned)K_)           Bsel = 4*L;
    else if (run + h0 + h1 >= (unsigned)K_)      Bsel = 4*L+1;
    else if (run + h0 + h1 + h2 >= (unsigned)K_) Bsel = 4*L+2;

    // pass 2: collect all candidates with bucket <= Bsel
    #pragma unroll 4
    for (int j = 0; j < 32; ++j){
        int c = j*64 + lane;
        float d = fmaf(-2.0f, dot3f(qx,qy,qz, xs[3*c], xs[3*c+1], xs[3*c+2]), sqq) + sqs[c];
        unsigned int f = flip_f32(d);
        if ((int)(f >> 24) <= Bsel){
            unsigned int pos = atomicAdd(&cnt[w], 1u);
            if (pos < LISTCAP) lst[w][pos] = ((unsigned long long)f << 32) | (unsigned int)c;
        }
    }
    __syncthreads();
    int m = (int)cnt[w]; if (m > LISTCAP) m = LISTCAP;

    int* outp = idx_out + ((size_t)b * N_ + q) * K_;
    for (int r = 0; r < K_; ++r){
        unsigned long long best = ~0ull;
        for (int i = lane; i < m; i += 64) best = umin64(best, lst[w][i]);
        #pragma unroll
        for (int off = 32; off; off >>= 1)
            best = umin64(best, (unsigned long long)__shfl_xor(best, off));
        for (int i = lane; i < m; i += 64) if (lst[w][i] == best) lst[w][i] = ~0ull;
        __threadfence_block();
        if (lane == 0) outp[r] = (int)(unsigned int)(best & 0xFFFFFFFFull);
    }
}

// ---------------- shared MLP helpers (identical codegen across kernels) ----------------
__device__ __forceinline__ void compute_h1(const float* __restrict__ xyz, const int* __restrict__ idx, int r,
                                           const float* W1s /*96*/, const float* b1s /*32*/, float* h1){
    int b = r >> 16;            // N_*K_ = 65536
    int n = (r >> 5) & (N_-1);
    int id = idx[r];
    const float* pc = xyz + ((size_t)b*N_ + n)*3;
    const float* pn = xyz + ((size_t)b*N_ + id)*3;
    float rx = pn[0]-pc[0], ry = pn[1]-pc[1], rz = pn[2]-pc[2];
    #pragma unroll
    for (int j = 0; j < H_; ++j){
        float a = fmaf(rx, W1s[j], fmaf(ry, W1s[H_+j], fmaf(rz, W1s[2*H_+j], b1s[j])));
        h1[j] = fmaxf(a, 0.0f);
    }
}

__device__ __forceinline__ void mlp12(const float* __restrict__ xyz, const int* __restrict__ idx, int r,
                                      const float* W1s, const float* b1s, const float* A1s /*a1|bb1*/,
                                      const float* W2s /*1024*/, const float* b2s /*32*/, float* h2){
    float h1[H_];
    compute_h1(xyz, idx, r, W1s, b1s, h1);
    #pragma unroll
    for (int j = 0; j < H_; ++j) h1[j] = fmaf(A1s[j], h1[j], A1s[H_+j]);
    #pragma unroll
    for (int j = 0; j < H_; ++j) h2[j] = b2s[j];
    #pragma unroll 4
    for (int hh = 0; hh < H_; ++hh){
        float c = h1[hh];
        #pragma unroll
        for (int j = 0; j < H_; ++j) h2[j] = fmaf(c, W2s[hh*H_+j], h2[j]);
    }
    #pragma unroll
    for (int j = 0; j < H_; ++j) h2[j] = fmaxf(h2[j], 0.0f);
}

// block-level per-channel sum/sumsq -> 64 global atomics per block
#define TSTRIDE 33
__device__ __forceinline__ void block_stats(float* tile /*256*33*/, const float* h,
                                            float* __restrict__ gsum, float* __restrict__ gsq){
    int tid = threadIdx.x;
    #pragma unroll
    for (int j = 0; j < H_; ++j) tile[tid*TSTRIDE + j] = h[j];
    __syncthreads();
    int cho = tid & 31, chunk = tid >> 5;
    float s = 0.f, q = 0.f;
    #pragma unroll
    for (int rr = 0; rr < 32; ++rr){
        float v = tile[(chunk*32 + rr)*TSTRIDE + cho];
        s += v; q = fmaf(v, v, q);
    }
    __syncthreads();
    tile[tid] = s; tile[256 + tid] = q;
    __syncthreads();
    if (tid < 32){
        float ss = 0.f, qq = 0.f;
        #pragma unroll
        for (int g = 0; g < 8; ++g){ ss += tile[g*32 + tid]; qq += tile[256 + g*32 + tid]; }
        atomicAdd(&gsum[tid], ss);
        atomicAdd(&gsq[tid], qq);
    }
}

__global__ __launch_bounds__(256) void k_h1stats(const float* __restrict__ xyz, const int* __restrict__ idx,
                                                 const float* __restrict__ W1, const float* __restrict__ b1,
                                                 float* gsum, float* gsq){
    __shared__ float W1s[4*H_];
    __shared__ float tile[256*TSTRIDE];
    int tid = threadIdx.x;
    if (tid < 4*H_) W1s[tid] = (tid < 3*H_) ? W1[tid] : b1[tid - 3*H_];
    __syncthreads();
    int r = blockIdx.x*256 + tid;
    float h1[H_];
    compute_h1(xyz, idx, r, W1s, W1s + 3*H_, h1);
    block_stats(tile, h1, gsum, gsq);
}

__global__ __launch_bounds__(256) void k_h2stats(const float* __restrict__ xyz, const int* __restrict__ idx,
                                                 const float* __restrict__ W1, const float* __restrict__ b1,
                                                 const float* __restrict__ a1, const float* __restrict__ bb1,
                                                 const float* __restrict__ W2, const float* __restrict__ b2,
                                                 float* gsum, float* gsq){
    __shared__ float W1s[4*H_];
    __shared__ float A1s[2*H_];
    __shared__ float W2s[H_*H_];
    __shared__ float b2s[H_];
    __shared__ float tile[256*TSTRIDE];
    int tid = threadIdx.x;
    if (tid < 4*H_) W1s[tid] = (tid < 3*H_) ? W1[tid] : b1[tid - 3*H_];
    if (tid >= 128 && tid < 192) A1s[tid-128] = (tid < 160) ? a1[tid-128] : bb1[tid-160];
    for (int i = tid; i < H_*H_; i += 256) W2s[i] = W2[i];
    if (tid < H_) b2s[tid] = b2[tid];
    __syncthreads();
    int r = blockIdx.x*256 + tid;
    float h2[H_];
    mlp12(xyz, idx, r, W1s, W1s + 3*H_, A1s, W2s, b2s, h2);
    block_stats(tile, h2, gsum, gsq);
}

__global__ void k_fin(const float* gsum, const float* gsq, const float* __restrict__ g,
                      const float* __restrict__ be, float invn, float* a, float* bb){
    int j = threadIdx.x;
    if (j < 32){
        float m = gsum[j] * invn;
        float v = gsq[j] * invn - m*m;
        float aj = g[j] / sqrtf(v + EPS_);
        a[j] = aj;
        bb[j] = fmaf(-aj, m, be[j]);
    }
}

// ---- prep: W3(f32) -> bf16 fragment-ordered Bl (K extended to 544 to fold gp.b3); zero stats ----
// Bl flat layout: ((kb*4 + q)*32 + col)*8 + j  <=>  B[k = kb*32+q*8+j][col], k<512: W3, 512..527: b3, else 0
__global__ __launch_bounds__(256) void k_prep(const float* __restrict__ W3, const float* __restrict__ b3,
                                              unsigned short* __restrict__ Blg, float* __restrict__ st){
    int flat = blockIdx.x*256 + threadIdx.x;
    if (flat < 17408){
        int j   = flat & 7;
        int col = (flat >> 3) & 31;
        int q   = (flat >> 8) & 3;
        int kb  = flat >> 10;
        int k   = kb*32 + q*8 + j;
        float val;
        if (k < 512) val = W3[(k >> 4)*512 + (k & 15)*32 + col];
        else { int c = k - 512; val = (c < 16) ? b3[c*32 + col] : 0.0f; }
        Blg[flat] = f2bf_rne(val);
    }
    if (blockIdx.x == 0){
        for (int i = threadIdx.x; i < 384; i += 256) st[i] = 0.f;
    }
}

// ---------------- main fused stage: mlp12 -> BN2 -> bf16 MFMA GEMM (K=544) -> max over k ----------------
// Per wave: 64 lanes compute 64 rows' h2n/gp; A-fragments built via intra-wave shuffles.
// MFMA 16x16x32: A[m=lane&15][k=(lane>>4)*8+j], B[k][n=lane&15], C col=lane&15 row=(lane>>4)*4+reg.
__global__ __launch_bounds__(256,4) void k_out(const float* __restrict__ xyz, const float* __restrict__ points,
                                               const int* __restrict__ idx,
                                               const float* __restrict__ W1, const float* __restrict__ b1,
                                               const float* __restrict__ a1, const float* __restrict__ bb1,
                                               const float* __restrict__ W2, const float* __restrict__ b2,
                                               const float* __restrict__ a2, const float* __restrict__ bb2,
                                               const unsigned short* __restrict__ Blg,
                                               float* __restrict__ out_pre, float* gsum, float* gsq){
    __shared__ uint4 Bls[2176];        // 34816 B: bf16 B-fragments, 17 kb-steps x 4 q x 32 cols x 8
    __shared__ float W2s[H_*H_];
    __shared__ float W1s[4*H_];
    __shared__ float A1s[2*H_];
    __shared__ float A2s[2*H_];
    __shared__ float b2s[H_];
    __shared__ float redS[COUT_], redQ[COUT_];
    int tid = threadIdx.x;
    for (int i = tid; i < 2176; i += 256) Bls[i] = ((const uint4*)Blg)[i];
    for (int i = tid; i < H_*H_; i += 256) W2s[i] = W2[i];
    if (tid < 4*H_) W1s[tid] = (tid < 3*H_) ? W1[tid] : b1[tid - 3*H_];
    if (tid >= 128 && tid < 192) A1s[tid-128] = (tid < 160) ? a1[tid-128] : bb1[tid-160];
    if (tid >= 192 && tid < 256) A2s[tid-192] = (tid < 224) ? a2[tid-192] : bb2[tid-224];
    if (tid < H_) b2s[tid] = b2[tid];
    if (tid < COUT_){ redS[tid] = 0.f; redQ[tid] = 0.f; }
    __syncthreads();

    int r = blockIdx.x*256 + tid;
    int b = r >> 16;
    int id = idx[r];

    float h2n[H_];
    mlp12(xyz, idx, r, W1s, W1s + 3*H_, A1s, W2s, b2s, h2n);
    #pragma unroll
    for (int h = 0; h < H_; ++h) h2n[h] = fmaf(A2s[h], h2n[h], A2s[H_+h]);

    float gp[CIN_];
    const float4* pp = (const float4*)(points + ((size_t)b*N_ + id)*CIN_);
    #pragma unroll
    for (int c4 = 0; c4 < CIN_/4; ++c4){
        float4 v = pp[c4];
        gp[4*c4] = v.x; gp[4*c4+1] = v.y; gp[4*c4+2] = v.z; gp[4*c4+3] = v.w;
    }

    const int lane = tid & 63;
    const int w    = tid >> 6;
    const int q    = lane >> 4;
    const int m    = lane & 15;

    #pragma unroll
    for (int p = 0; p < 2; ++p){           // two (b,n)-groups of 32 rows per wave
        float pv0 = -3.4e38f, pv1 = -3.4e38f;
        #pragma unroll
        for (int tp = 0; tp < 2; ++tp){    // two 16-row MFMA tiles per group
            const int tile = p*2 + tp;
            const int src  = tile*16 + m;  // source lane holding this tile-row's h2n/gp
            float gpr[8];
            #pragma unroll
            for (int j = 0; j < 8; ++j){
                float lo = __shfl(gp[j],     src, 64);
                float hi = __shfl(gp[8 + j], src, 64);
                gpr[j] = (q & 1) ? hi : lo;
            }
            f32x4 acc0 = {0.f,0.f,0.f,0.f}, acc1 = {0.f,0.f,0.f,0.f};
            #pragma unroll
            for (int kb = 0; kb < 17; ++kb){
                float hv;
                if (kb < 16){
                    float he = __shfl(h2n[2*kb],     src, 64);
                    float ho = __shfl(h2n[2*kb + 1], src, 64);
                    hv = (q >> 1) ? ho : he;
                } else {
                    hv = (q < 2) ? 1.0f : 0.0f;     // b3 fold: v[512+c] = gp[c]
                }
                union { unsigned int u[4]; short8 s8; } af;
                #pragma unroll
                for (int jj = 0; jj < 4; ++jj){
                    float p0 = hv * gpr[2*jj];
                    float p1 = hv * gpr[2*jj + 1];
                    af.u[jj] = __builtin_amdgcn_perm(__float_as_uint(p1), __float_as_uint(p0), 0x07060302u);
                }
                union { uint4 u4; short8 s8; } bf0, bf1;
                bf0.u4 = Bls[(kb*4 + q)*32 + m];
                bf1.u4 = Bls[(kb*4 + q)*32 + 16 + m];
                acc0 = __builtin_amdgcn_mfma_f32_16x16x32_bf16(af.s8, bf0.s8, acc0, 0, 0, 0);
                acc1 = __builtin_amdgcn_mfma_f32_16x16x32_bf16(af.s8, bf1.s8, acc1, 0, 0, 0);
            }
            float v0 = fmaxf(fmaxf(acc0[0], acc0[1]), fmaxf(acc0[2], acc0[3]));
            float v1 = fmaxf(fmaxf(acc1[0], acc1[1]), fmaxf(acc1[2], acc1[3]));
            pv0 = fmaxf(pv0, v0);
            pv1 = fmaxf(pv1, v1);
        }
        // reduce across the 4 q-groups (rows within the 32-row group)
        pv0 = fmaxf(pv0, __shfl_xor(pv0, 16, 64));
        pv0 = fmaxf(pv0, __shfl_xor(pv0, 32, 64));
        pv1 = fmaxf(pv1, __shfl_xor(pv1, 16, 64));
        pv1 = fmaxf(pv1, __shfl_xor(pv1, 32, 64));
        if (lane < 32){
            float v = (lane < 16) ? pv0 : pv1;     // lane l -> output channel l
            int g = blockIdx.x*8 + w*2 + p;        // (b,n) group id
            out_pre[(size_t)g*COUT_ + lane] = v;
            atomicAdd(&redS[lane], v);
            atomicAdd(&redQ[lane], v*v);
        }
    }
    __syncthreads();
    if (tid < COUT_){
        atomicAdd(&gsum[tid], redS[tid]);
        atomicAdd(&gsq[tid],  redQ[tid]);
    }
}

__global__ __launch_bounds__(256) void k_bn(const float* __restrict__ out_pre, const float* __restrict__ a,
                                            const float* __restrict__ bb, float* __restrict__ out){
    int i = blockIdx.x*256 + threadIdx.x;
    int o = i & (COUT_-1);
    out[i] = fmaf(a[o], out_pre[i], bb[o]);
}

extern "C" void kernel_launch(void* const* d_in, const int* in_sizes, int n_in,
                              void* d_out, int out_size, void* d_ws, size_t ws_size,
                              hipStream_t stream){
    const float* xyz    = (const float*)d_in[0];
    const float* points = (const float*)d_in[1];
    const float* W1  = (const float*)d_in[2];
    const float* b1  = (const float*)d_in[3];
    const float* g1  = (const float*)d_in[4];
    const float* be1 = (const float*)d_in[5];
    const float* W2  = (const float*)d_in[6];
    const float* b2  = (const float*)d_in[7];
    const float* g2  = (const float*)d_in[8];
    const float* be2 = (const float*)d_in[9];
    const float* W3  = (const float*)d_in[10];
    const float* b3  = (const float*)d_in[11];
    const float* gbn = (const float*)d_in[12];
    const float* bbn = (const float*)d_in[13];
    float* out = (float*)d_out;

    // ws layout (floats): idx[R_] | out_pre[B_*N_*COUT_] | st[384] | Bl bf16[17408]
    int*   idx     = (int*)d_ws;
    float* out_pre = (float*)d_ws + R_;
    float* st      = out_pre + (size_t)B_*N_*COUT_;
    unsigned short* Blg = (unsigned short*)(st + 384);
    float *s1=st, *q1=st+32, *s2=st+64, *q2=st+96, *s3=st+128, *q3=st+160;
    float *a1=st+192, *bb1=st+224, *a2=st+256, *bb2=st+288, *a3=st+320, *bb3=st+352;

    hipLaunchKernelGGL(k_prep,    dim3(68),            dim3(256), 0, stream, W3, b3, Blg, st);
    hipLaunchKernelGGL(k_knn,     dim3(B_*(N_/QPB)),   dim3(256), 0, stream, xyz, idx);
    hipLaunchKernelGGL(k_h1stats, dim3(R_/256),        dim3(256), 0, stream, xyz, idx, W1, b1, s1, q1);
    hipLaunchKernelGGL(k_fin,     dim3(1),             dim3(64),  0, stream, s1, q1, g1, be1, 1.0f/(float)R_, a1, bb1);
    hipLaunchKernelGGL(k_h2stats, dim3(R_/256),        dim3(256), 0, stream, xyz, idx, W1, b1, a1, bb1, W2, b2, s2, q2);
    hipLaunchKernelGGL(k_fin,     dim3(1),             dim3(64),  0, stream, s2, q2, g2, be2, 1.0f/(float)R_, a2, bb2);
    hipLaunchKernelGGL(k_out,     dim3(R_/256),        dim3(256), 0, stream, xyz, points, idx, W1, b1, a1, bb1,
                       W2, b2, a2, bb2, Blg, out_pre, s3, q3);
    hipLaunchKernelGGL(k_fin,     dim3(1),             dim3(64),  0, stream, s3, q3, gbn, bbn, 1.0f/(float)(B_*N_), a3, bb3);
    hipLaunchKernelGGL(k_bn,      dim3(B_*N_*COUT_/256), dim3(256), 0, stream, out_pre, a3, bb3, out);
}

// Round 3
// 264.466 us; speedup vs baseline: 1.8085x; 1.3971x over previous
//
#include <hip/hip_runtime.h>

#define B_ 4
#define N_ 2048
#define K_ 32
#define CIN_ 16
#define COUT_ 32
#define H_ 32
#define R_ (B_*N_*K_)      // 262144 rows through the weight-net
#define EPS_ 1e-5f
#define QPB 4              // queries (waves) per block in knn
#define LISTCAP 384

typedef __attribute__((ext_vector_type(8))) short short8;
typedef __attribute__((ext_vector_type(4))) float f32x4;

// identical fma association everywhere so self-distance is exactly 0 and
// recomputed h1/h2 match the stats-pass values bit-for-bit
__device__ __forceinline__ float dot3f(float ax,float ay,float az,float bx,float by,float bz){
    return fmaf(az,bz, fmaf(ay,by, ax*bx));
}
__device__ __forceinline__ unsigned int flip_f32(float d){
    unsigned int u = __float_as_uint(d);
    return u ^ ((unsigned int)(((int)u) >> 31) | 0x80000000u);  // total order
}
__device__ __forceinline__ unsigned short f2bf_rne(float x){
    unsigned int u = __float_as_uint(x);
    unsigned int r = u + 0x7FFFu + ((u >> 16) & 1u);
    return (unsigned short)(r >> 16);
}

// ---------------- KNN: exact top-32 smallest dist, tie -> smallest index ----------------
// LDS-pipe-lean: b128 point reads, parity-replicated histogram, ballot compaction,
// O(m^2) rank-select with broadcast reads (replaces 32-round extract-min).
__global__ __launch_bounds__(256) void k_knn(const float* __restrict__ xyz, int* __restrict__ idx_out){
    __shared__ float4 xs4[N_];                        // 32 KB  (x,y,z,|p|^2)
    __shared__ unsigned int hist[QPB][256][2];        // 8 KB   parity replicas -> adjacent banks
    __shared__ unsigned long long lst[QPB][LISTCAP];  // 12 KB

    const int tid  = threadIdx.x;
    const int w    = tid >> 6;
    const int lane = tid & 63;
    const int b    = blockIdx.x / (N_/QPB);
    const int q    = (blockIdx.x % (N_/QPB)) * QPB + w;   // query index within batch

    const float* xb = xyz + (size_t)b * N_ * 3;
    for (int i = tid; i < N_; i += 256){
        float x = xb[3*i], y = xb[3*i+1], z = xb[3*i+2];
        xs4[i] = make_float4(x, y, z, dot3f(x,y,z,x,y,z));
    }
    for (int i = lane; i < 512; i += 64) ((unsigned int*)hist[w])[i] = 0u;
    __syncthreads();

    const float4 qp = xs4[q];        // wave-uniform broadcast
    const float qx = qp.x, qy = qp.y, qz = qp.z, sqq = qp.w;

    // pass 1: histogram of top-8-bits of order-flipped distance
    #pragma unroll 4
    for (int j = 0; j < 32; ++j){
        int c = j*64 + lane;
        float4 pt = xs4[c];
        float d = fmaf(-2.0f, dot3f(qx,qy,qz, pt.x,pt.y,pt.z), sqq) + pt.w;
        atomicAdd(&hist[w][flip_f32(d) >> 24][lane & 1], 1u);
    }
    __syncthreads();

    // threshold: smallest bucket Bsel with cumulative count >= K_
    uint4 ha = ((const uint4*)hist[w])[2*lane];       // buckets 4L..4L+1 (both replicas)
    uint4 hb = ((const uint4*)hist[w])[2*lane+1];     // buckets 4L+2..4L+3
    unsigned int g0 = ha.x + ha.y, g1 = ha.z + ha.w, g2 = hb.x + hb.y, g3 = hb.z + hb.w;
    unsigned int gs = g0 + g1 + g2 + g3;
    unsigned int cum = gs;
    #pragma unroll
    for (int off = 1; off < 64; off <<= 1){
        unsigned int v = __shfl_up(cum, off);
        if (lane >= off) cum += v;
    }
    unsigned long long bal = __ballot(cum >= (unsigned)K_);
    int L = __ffsll(bal) - 1;
    unsigned int run = __shfl(cum, L) - __shfl(gs, L);   // exclusive prefix before group L
    unsigned int h0 = __shfl(g0, L), h1 = __shfl(g1, L), h2 = __shfl(g2, L);
    int Bsel = 4*L + 3;
    if      (run + h0 >= (unsigned)K_)           Bsel = 4*L;
    else if (run + h0 + h1 >= (unsigned)K_)      Bsel = 4*L + 1;
    else if (run + h0 + h1 + h2 >= (unsigned)K_) Bsel = 4*L + 2;

    // pass 2: ballot-compact all candidates with bucket <= Bsel
    const unsigned long long mlt = (lane == 63) ? ~0ull >> 1 : (1ull << lane) - 1ull;
    unsigned int cnt = 0;
    #pragma unroll 4
    for (int j = 0; j < 32; ++j){
        int c = j*64 + lane;
        float4 pt = xs4[c];
        float d = fmaf(-2.0f, dot3f(qx,qy,qz, pt.x,pt.y,pt.z), sqq) + pt.w;
        unsigned int f = flip_f32(d);
        bool surv = (int)(f >> 24) <= Bsel;
        unsigned long long sb = __ballot(surv);
        if (sb){
            unsigned int pos = cnt + (unsigned int)__popcll(sb & mlt);
            if (surv && pos < (unsigned)LISTCAP)
                lst[w][pos] = ((unsigned long long)f << 32) | (unsigned int)c;
            cnt += (unsigned int)__popcll(sb);
        }
    }
    int m = (int)cnt; if (m > LISTCAP) m = LISTCAP;

    // rank-select: rank_i = #{j : key_j < key_i}; keys unique (idx in low bits) -> exact
    int* outp = idx_out + ((size_t)b * N_ + q) * K_;
    for (int i = lane; i < m; i += 64){
        unsigned long long my = lst[w][i];
        int rank = 0;
        for (int jj = 0; jj < m; ++jj)           // wave-uniform broadcast reads
            rank += (lst[w][jj] < my) ? 1 : 0;
        if (rank < K_) outp[rank] = (int)(unsigned int)(my & 0xFFFFFFFFull);
    }
}

// ---------------- shared MLP helpers (identical codegen across kernels) ----------------
__device__ __forceinline__ void compute_h1(const float* __restrict__ xyz, const int* __restrict__ idx, int r,
                                           const float* W1s /*96*/, const float* b1s /*32*/, float* h1){
    int b = r >> 16;            // N_*K_ = 65536
    int n = (r >> 5) & (N_-1);
    int id = idx[r];
    const float* pc = xyz + ((size_t)b*N_ + n)*3;
    const float* pn = xyz + ((size_t)b*N_ + id)*3;
    float rx = pn[0]-pc[0], ry = pn[1]-pc[1], rz = pn[2]-pc[2];
    #pragma unroll
    for (int j = 0; j < H_; ++j){
        float a = fmaf(rx, W1s[j], fmaf(ry, W1s[H_+j], fmaf(rz, W1s[2*H_+j], b1s[j])));
        h1[j] = fmaxf(a, 0.0f);
    }
}

__device__ __forceinline__ void mlp12(const float* __restrict__ xyz, const int* __restrict__ idx, int r,
                                      const float* W1s, const float* b1s, const float* A1s /*a1|bb1*/,
                                      const float* W2s /*1024*/, const float* b2s /*32*/, float* h2){
    float h1[H_];
    compute_h1(xyz, idx, r, W1s, b1s, h1);
    #pragma unroll
    for (int j = 0; j < H_; ++j) h1[j] = fmaf(A1s[j], h1[j], A1s[H_+j]);
    #pragma unroll
    for (int j = 0; j < H_; ++j) h2[j] = b2s[j];
    #pragma unroll 4
    for (int hh = 0; hh < H_; ++hh){
        float c = h1[hh];
        #pragma unroll
        for (int j = 0; j < H_; ++j) h2[j] = fmaf(c, W2s[hh*H_+j], h2[j]);
    }
    #pragma unroll
    for (int j = 0; j < H_; ++j) h2[j] = fmaxf(h2[j], 0.0f);
}

// block-level per-channel sum/sumsq -> 64 global atomics per block
#define TSTRIDE 33
__device__ __forceinline__ void block_stats(float* tile /*256*33*/, const float* h,
                                            float* __restrict__ gsum, float* __restrict__ gsq){
    int tid = threadIdx.x;
    #pragma unroll
    for (int j = 0; j < H_; ++j) tile[tid*TSTRIDE + j] = h[j];
    __syncthreads();
    int cho = tid & 31, chunk = tid >> 5;
    float s = 0.f, q = 0.f;
    #pragma unroll
    for (int rr = 0; rr < 32; ++rr){
        float v = tile[(chunk*32 + rr)*TSTRIDE + cho];
        s += v; q = fmaf(v, v, q);
    }
    __syncthreads();
    tile[tid] = s; tile[256 + tid] = q;
    __syncthreads();
    if (tid < 32){
        float ss = 0.f, qq = 0.f;
        #pragma unroll
        for (int g = 0; g < 8; ++g){ ss += tile[g*32 + tid]; qq += tile[256 + g*32 + tid]; }
        atomicAdd(&gsum[tid], ss);
        atomicAdd(&gsq[tid], qq);
    }
}

__global__ __launch_bounds__(256) void k_h1stats(const float* __restrict__ xyz, const int* __restrict__ idx,
                                                 const float* __restrict__ W1, const float* __restrict__ b1,
                                                 float* gsum, float* gsq){
    __shared__ float W1s[4*H_];
    __shared__ float tile[256*TSTRIDE];
    int tid = threadIdx.x;
    if (tid < 4*H_) W1s[tid] = (tid < 3*H_) ? W1[tid] : b1[tid - 3*H_];
    __syncthreads();
    int r = blockIdx.x*256 + tid;
    float h1[H_];
    compute_h1(xyz, idx, r, W1s, W1s + 3*H_, h1);
    block_stats(tile, h1, gsum, gsq);
}

__global__ __launch_bounds__(256) void k_h2stats(const float* __restrict__ xyz, const int* __restrict__ idx,
                                                 const float* __restrict__ W1, const float* __restrict__ b1,
                                                 const float* __restrict__ a1, const float* __restrict__ bb1,
                                                 const float* __restrict__ W2, const float* __restrict__ b2,
                                                 float* gsum, float* gsq){
    __shared__ float W1s[4*H_];
    __shared__ float A1s[2*H_];
    __shared__ float W2s[H_*H_];
    __shared__ float b2s[H_];
    __shared__ float tile[256*TSTRIDE];
    int tid = threadIdx.x;
    if (tid < 4*H_) W1s[tid] = (tid < 3*H_) ? W1[tid] : b1[tid - 3*H_];
    if (tid >= 128 && tid < 192) A1s[tid-128] = (tid < 160) ? a1[tid-128] : bb1[tid-160];
    for (int i = tid; i < H_*H_; i += 256) W2s[i] = W2[i];
    if (tid < H_) b2s[tid] = b2[tid];
    __syncthreads();
    int r = blockIdx.x*256 + tid;
    float h2[H_];
    mlp12(xyz, idx, r, W1s, W1s + 3*H_, A1s, W2s, b2s, h2);
    block_stats(tile, h2, gsum, gsq);
}

__global__ void k_fin(const float* gsum, const float* gsq, const float* __restrict__ g,
                      const float* __restrict__ be, float invn, float* a, float* bb){
    int j = threadIdx.x;
    if (j < 32){
        float m = gsum[j] * invn;
        float v = gsq[j] * invn - m*m;
        float aj = g[j] / sqrtf(v + EPS_);
        a[j] = aj;
        bb[j] = fmaf(-aj, m, be[j]);
    }
}

// ---- prep: W3(f32) -> bf16 fragment-ordered Bl (K extended to 544 to fold gp.b3); zero stats ----
__global__ __launch_bounds__(256) void k_prep(const float* __restrict__ W3, const float* __restrict__ b3,
                                              unsigned short* __restrict__ Blg, float* __restrict__ st){
    int flat = blockIdx.x*256 + threadIdx.x;
    if (flat < 17408){
        int j   = flat & 7;
        int col = (flat >> 3) & 31;
        int q   = (flat >> 8) & 3;
        int kb  = flat >> 10;
        int k   = kb*32 + q*8 + j;
        float val;
        if (k < 512) val = W3[(k >> 4)*512 + (k & 15)*32 + col];
        else { int c = k - 512; val = (c < 16) ? b3[c*32 + col] : 0.0f; }
        Blg[flat] = f2bf_rne(val);
    }
    if (blockIdx.x == 0){
        for (int i = threadIdx.x; i < 384; i += 256) st[i] = 0.f;
    }
}

// ---------------- main fused stage: mlp12 -> BN2 -> bf16 MFMA GEMM (K=544) -> max over k ----------------
// __launch_bounds__(256,2): (256,4) capped VGPRs at 64 -> ~300 MB/dispatch scratch spill (round-2 lesson)
__global__ __launch_bounds__(256,2) void k_out(const float* __restrict__ xyz, const float* __restrict__ points,
                                               const int* __restrict__ idx,
                                               const float* __restrict__ W1, const float* __restrict__ b1,
                                               const float* __restrict__ a1, const float* __restrict__ bb1,
                                               const float* __restrict__ W2, const float* __restrict__ b2,
                                               const float* __restrict__ a2, const float* __restrict__ bb2,
                                               const unsigned short* __restrict__ Blg,
                                               float* __restrict__ out_pre, float* gsum, float* gsq){
    __shared__ uint4 Bls[2176];        // 34816 B: bf16 B-fragments, 17 kb-steps x 4 q x 32 cols x 8
    __shared__ float W2s[H_*H_];
    __shared__ float W1s[4*H_];
    __shared__ float A1s[2*H_];
    __shared__ float A2s[2*H_];
    __shared__ float b2s[H_];
    __shared__ float redS[COUT_], redQ[COUT_];
    int tid = threadIdx.x;
    for (int i = tid; i < 2176; i += 256) Bls[i] = ((const uint4*)Blg)[i];
    for (int i = tid; i < H_*H_; i += 256) W2s[i] = W2[i];
    if (tid < 4*H_) W1s[tid] = (tid < 3*H_) ? W1[tid] : b1[tid - 3*H_];
    if (tid >= 128 && tid < 192) A1s[tid-128] = (tid < 160) ? a1[tid-128] : bb1[tid-160];
    if (tid >= 192 && tid < 256) A2s[tid-192] = (tid < 224) ? a2[tid-192] : bb2[tid-224];
    if (tid < H_) b2s[tid] = b2[tid];
    if (tid < COUT_){ redS[tid] = 0.f; redQ[tid] = 0.f; }
    __syncthreads();

    int r = blockIdx.x*256 + tid;
    int b = r >> 16;
    int id = idx[r];

    float h2n[H_];
    mlp12(xyz, idx, r, W1s, W1s + 3*H_, A1s, W2s, b2s, h2n);
    #pragma unroll
    for (int h = 0; h < H_; ++h) h2n[h] = fmaf(A2s[h], h2n[h], A2s[H_+h]);

    float gp[CIN_];
    const float4* pp = (const float4*)(points + ((size_t)b*N_ + id)*CIN_);
    #pragma unroll
    for (int c4 = 0; c4 < CIN_/4; ++c4){
        float4 v = pp[c4];
        gp[4*c4] = v.x; gp[4*c4+1] = v.y; gp[4*c4+2] = v.z; gp[4*c4+3] = v.w;
    }

    const int lane = tid & 63;
    const int w    = tid >> 6;
    const int q    = lane >> 4;
    const int m    = lane & 15;

    #pragma unroll
    for (int p = 0; p < 2; ++p){           // two (b,n)-groups of 32 rows per wave
        float pv0 = -3.4e38f, pv1 = -3.4e38f;
        #pragma unroll
        for (int tp = 0; tp < 2; ++tp){    // two 16-row MFMA tiles per group
            const int tile = p*2 + tp;
            const int src  = tile*16 + m;  // source lane holding this tile-row's h2n/gp
            float gpr[8];
            #pragma unroll
            for (int j = 0; j < 8; ++j){
                float lo = __shfl(gp[j],     src, 64);
                float hi = __shfl(gp[8 + j], src, 64);
                gpr[j] = (q & 1) ? hi : lo;
            }
            f32x4 acc0 = {0.f,0.f,0.f,0.f}, acc1 = {0.f,0.f,0.f,0.f};
            #pragma unroll
            for (int kb = 0; kb < 17; ++kb){
                float hv;
                if (kb < 16){
                    float he = __shfl(h2n[2*kb],     src, 64);
                    float ho = __shfl(h2n[2*kb + 1], src, 64);
                    hv = (q >> 1) ? ho : he;
                } else {
                    hv = (q < 2) ? 1.0f : 0.0f;     // b3 fold: v[512+c] = gp[c]
                }
                union { unsigned int u[4]; short8 s8; } af;
                #pragma unroll
                for (int jj = 0; jj < 4; ++jj){
                    float p0 = hv * gpr[2*jj];
                    float p1 = hv * gpr[2*jj + 1];
                    af.u[jj] = __builtin_amdgcn_perm(__float_as_uint(p1), __float_as_uint(p0), 0x07060302u);
                }
                union { uint4 u4; short8 s8; } bf0, bf1;
                bf0.u4 = Bls[(kb*4 + q)*32 + m];
                bf1.u4 = Bls[(kb*4 + q)*32 + 16 + m];
                acc0 = __builtin_amdgcn_mfma_f32_16x16x32_bf16(af.s8, bf0.s8, acc0, 0, 0, 0);
                acc1 = __builtin_amdgcn_mfma_f32_16x16x32_bf16(af.s8, bf1.s8, acc1, 0, 0, 0);
            }
            float v0 = fmaxf(fmaxf(acc0[0], acc0[1]), fmaxf(acc0[2], acc0[3]));
            float v1 = fmaxf(fmaxf(acc1[0], acc1[1]), fmaxf(acc1[2], acc1[3]));
            pv0 = fmaxf(pv0, v0);
            pv1 = fmaxf(pv1, v1);
        }
        // reduce across the 4 q-groups (rows within the 32-row group)
        pv0 = fmaxf(pv0, __shfl_xor(pv0, 16, 64));
        pv0 = fmaxf(pv0, __shfl_xor(pv0, 32, 64));
        pv1 = fmaxf(pv1, __shfl_xor(pv1, 16, 64));
        pv1 = fmaxf(pv1, __shfl_xor(pv1, 32, 64));
        if (lane < 32){
            float v = (lane < 16) ? pv0 : pv1;     // lane l -> output channel l
            int g = blockIdx.x*8 + w*2 + p;        // (b,n) group id
            out_pre[(size_t)g*COUT_ + lane] = v;
            atomicAdd(&redS[lane], v);
            atomicAdd(&redQ[lane], v*v);
        }
    }
    __syncthreads();
    if (tid < COUT_){
        atomicAdd(&gsum[tid], redS[tid]);
        atomicAdd(&gsq[tid],  redQ[tid]);
    }
}

__global__ __launch_bounds__(256) void k_bn(const float* __restrict__ out_pre, const float* __restrict__ a,
                                            const float* __restrict__ bb, float* __restrict__ out){
    int i = blockIdx.x*256 + threadIdx.x;
    int o = i & (COUT_-1);
    out[i] = fmaf(a[o], out_pre[i], bb[o]);
}

extern "C" void kernel_launch(void* const* d_in, const int* in_sizes, int n_in,
                              void* d_out, int out_size, void* d_ws, size_t ws_size,
                              hipStream_t stream){
    const float* xyz    = (const float*)d_in[0];
    const float* points = (const float*)d_in[1];
    const float* W1  = (const float*)d_in[2];
    const float* b1  = (const float*)d_in[3];
    const float* g1  = (const float*)d_in[4];
    const float* be1 = (const float*)d_in[5];
    const float* W2  = (const float*)d_in[6];
    const float* b2  = (const float*)d_in[7];
    const float* g2  = (const float*)d_in[8];
    const float* be2 = (const float*)d_in[9];
    const float* W3  = (const float*)d_in[10];
    const float* b3  = (const float*)d_in[11];
    const float* gbn = (const float*)d_in[12];
    const float* bbn = (const float*)d_in[13];
    float* out = (float*)d_out;

    // ws layout (floats): idx[R_] | out_pre[B_*N_*COUT_] | st[384] | Bl bf16[17408]
    int*   idx     = (int*)d_ws;
    float* out_pre = (float*)d_ws + R_;
    float* st      = out_pre + (size_t)B_*N_*COUT_;
    unsigned short* Blg = (unsigned short*)(st + 384);
    float *s1=st, *q1=st+32, *s2=st+64, *q2=st+96, *s3=st+128, *q3=st+160;
    float *a1=st+192, *bb1=st+224, *a2=st+256, *bb2=st+288, *a3=st+320, *bb3=st+352;

    hipLaunchKernelGGL(k_prep,    dim3(68),            dim3(256), 0, stream, W3, b3, Blg, st);
    hipLaunchKernelGGL(k_knn,     dim3(B_*(N_/QPB)),   dim3(256), 0, stream, xyz, idx);
    hipLaunchKernelGGL(k_h1stats, dim3(R_/256),        dim3(256), 0, stream, xyz, idx, W1, b1, s1, q1);
    hipLaunchKernelGGL(k_fin,     dim3(1),             dim3(64),  0, stream, s1, q1, g1, be1, 1.0f/(float)R_, a1, bb1);
    hipLaunchKernelGGL(k_h2stats, dim3(R_/256),        dim3(256), 0, stream, xyz, idx, W1, b1, a1, bb1, W2, b2, s2, q2);
    hipLaunchKernelGGL(k_fin,     dim3(1),             dim3(64),  0, stream, s2, q2, g2, be2, 1.0f/(float)R_, a2, bb2);
    hipLaunchKernelGGL(k_out,     dim3(R_/256),        dim3(256), 0, stream, xyz, points, idx, W1, b1, a1, bb1,
                       W2, b2, a2, bb2, Blg, out_pre, s3, q3);
    hipLaunchKernelGGL(k_fin,     dim3(1),             dim3(64),  0, stream, s3, q3, gbn, bbn, 1.0f/(float)(B_*N_), a3, bb3);
    hipLaunchKernelGGL(k_bn,      dim3(B_*N_*COUT_/256), dim3(256), 0, stream, out_pre, a3, bb3, out);
}

// Round 4
// 230.486 us; speedup vs baseline: 2.0752x; 1.1474x over previous
//
#include <hip/hip_runtime.h>

#define B_ 4
#define N_ 2048
#define K_ 32
#define CIN_ 16
#define COUT_ 32
#define H_ 32
#define R_ (B_*N_*K_)      // 262144 rows through the weight-net
#define EPS_ 1e-5f
#define INVR_ (1.0f/(float)R_)
#define INVBN_ (1.0f/(float)(B_*N_))
#define QPB 4              // queries (waves) per block in knn
#define LISTCAP 384

typedef __attribute__((ext_vector_type(8))) short short8;
typedef __attribute__((ext_vector_type(4))) float f32x4;

// identical fma association everywhere so self-distance is exactly 0
__device__ __forceinline__ float dot3f(float ax,float ay,float az,float bx,float by,float bz){
    return fmaf(az,bz, fmaf(ay,by, ax*bx));
}
__device__ __forceinline__ unsigned int flip_f32(float d){
    unsigned int u = __float_as_uint(d);
    return u ^ ((unsigned int)(((int)u) >> 31) | 0x80000000u);  // total order
}
__device__ __forceinline__ unsigned short f2bf_rne(float x){
    unsigned int u = __float_as_uint(x);
    unsigned int r = u + 0x7FFFu + ((u >> 16) & 1u);
    return (unsigned short)(r >> 16);
}

// wave-local histogram select: smallest bucket with cumulative >= Kthr; below = strict-below count
__device__ __forceinline__ void hsel(const unsigned int* hw /*512 = 256 buckets x2 replicas*/, int lane,
                                     unsigned int Kthr, int* Bsel, unsigned int* below){
    uint4 ha = ((const uint4*)hw)[2*lane];
    uint4 hb = ((const uint4*)hw)[2*lane+1];
    unsigned int g0 = ha.x+ha.y, g1 = ha.z+ha.w, g2 = hb.x+hb.y, g3 = hb.z+hb.w;
    unsigned int gs = g0+g1+g2+g3, cum = gs;
    #pragma unroll
    for (int off = 1; off < 64; off <<= 1){
        unsigned int v = __shfl_up(cum, off);
        if (lane >= off) cum += v;
    }
    unsigned long long bal = __ballot(cum >= Kthr);
    int L = __ffsll(bal) - 1;
    unsigned int run = __shfl(cum, L) - __shfl(gs, L);
    unsigned int h0 = __shfl(g0, L), h1 = __shfl(g1, L), h2 = __shfl(g2, L);
    if      (run + h0 >= Kthr)           { *Bsel = 4*L;     *below = run; }
    else if (run + h0 + h1 >= Kthr)      { *Bsel = 4*L + 1; *below = run + h0; }
    else if (run + h0 + h1 + h2 >= Kthr) { *Bsel = 4*L + 2; *below = run + h0 + h1; }
    else                                 { *Bsel = 4*L + 3; *below = run + h0 + h1 + h2; }
}

// ---------------- KNN: exact top-32 smallest dist, tie -> smallest index ----------------
// Two-level 8+8-bit radix refinement (f>>24 is only sign+7exp -> coarse bucket can hold
// hundreds; refining on bits 23:16 bounds survivor count to ~K + a few). Lane caches its
// 32 flipped distances in regs, so refine+compact passes cost zero LDS reads.
__global__ __launch_bounds__(256) void k_knn(const float* __restrict__ xyz, int* __restrict__ idx_out){
    __shared__ float4 xs4[N_];                        // 32 KB  (x,y,z,|p|^2)
    __shared__ unsigned int hist[QPB][256][2];        // 8 KB   parity replicas
    __shared__ unsigned long long lst[QPB][LISTCAP];  // 12 KB

    const int tid  = threadIdx.x;
    const int w    = tid >> 6;
    const int lane = tid & 63;
    const int b    = blockIdx.x / (N_/QPB);
    const int q    = (blockIdx.x % (N_/QPB)) * QPB + w;

    const float* xb = xyz + (size_t)b * N_ * 3;
    for (int i = tid; i < N_; i += 256){
        float x = xb[3*i], y = xb[3*i+1], z = xb[3*i+2];
        xs4[i] = make_float4(x, y, z, dot3f(x,y,z,x,y,z));
    }
    for (int i = lane; i < 512; i += 64) ((unsigned int*)hist[w])[i] = 0u;
    __syncthreads();   // only cross-wave dep: xs4. hist/lst are wave-private below.

    const float4 qp = xs4[q];
    const float qx = qp.x, qy = qp.y, qz = qp.z, sqq = qp.w;

    // pass 1: compute+cache flipped distances, coarse histogram (sign+7exp bits)
    unsigned int fv[32];
    #pragma unroll
    for (int j = 0; j < 32; ++j){
        int c = j*64 + lane;
        float4 pt = xs4[c];
        float d = fmaf(-2.0f, dot3f(qx,qy,qz, pt.x,pt.y,pt.z), sqq) + pt.w;
        unsigned int f = flip_f32(d);
        fv[j] = f;
        atomicAdd(&hist[w][f >> 24][lane & 1], 1u);
    }
    int B0; unsigned int lt0;
    hsel(&hist[w][0][0], lane, (unsigned)K_, &B0, &lt0);
    unsigned int Kp = (unsigned)K_ - lt0;   // still needed from within bucket B0 (>=1)

    // pass 1b: refine bucket B0 on bits 23:16 (1 exp + 7 mantissa)
    for (int i = lane; i < 512; i += 64) ((unsigned int*)hist[w])[i] = 0u;
    #pragma unroll
    for (int j = 0; j < 32; ++j){
        if ((int)(fv[j] >> 24) == B0)
            atomicAdd(&hist[w][(fv[j] >> 16) & 0xFF][lane & 1], 1u);
    }
    int B1; unsigned int lt1;
    hsel(&hist[w][0][0], lane, Kp, &B1, &lt1);

    // pass 2: ballot-compact survivors (m ~ K + ties in one 16-bit bucket)
    const unsigned long long mlt = (lane == 63) ? ~0ull >> 1 : (1ull << lane) - 1ull;
    unsigned int cnt = 0;
    #pragma unroll
    for (int j = 0; j < 32; ++j){
        unsigned int f = fv[j];
        int top = (int)(f >> 24);
        bool surv = (top < B0) || (top == B0 && (int)((f >> 16) & 0xFF) <= B1);
        unsigned long long sb = __ballot(surv);
        unsigned int pos = cnt + (unsigned int)__popcll(sb & mlt);
        if (surv && pos < (unsigned)LISTCAP)
            lst[w][pos] = ((unsigned long long)f << 32) | (unsigned int)(j*64 + lane);
        cnt += (unsigned int)__popcll(sb);
    }
    int m = (int)cnt; if (m > LISTCAP) m = LISTCAP;

    // rank-select: keys unique (idx in low bits) -> exact permutation, top_k tie-break
    int* outp = idx_out + ((size_t)b * N_ + q) * K_;
    for (int i = lane; i < m; i += 64){
        unsigned long long my = lst[w][i];
        int rank = 0;
        for (int jj = 0; jj < m; ++jj)
            rank += (lst[w][jj] < my) ? 1 : 0;
        if (rank < K_) outp[rank] = (int)(unsigned int)(my & 0xFFFFFFFFull);
    }
}

// ---------------- MLP helpers: weights/BN params read straight from global ----------------
// uniform addresses -> compiler emits s_load on the scalar pipe (no LDS, no VGPR cost)
__device__ __forceinline__ void compute_h1(const float* __restrict__ xyz, const int* __restrict__ idx, int r,
                                           const float* __restrict__ W1, const float* __restrict__ b1, float* h1){
    int b = r >> 16;            // N_*K_ = 65536
    int n = (r >> 5) & (N_-1);
    int id = idx[r];
    const float* pc = xyz + ((size_t)b*N_ + n)*3;
    const float* pn = xyz + ((size_t)b*N_ + id)*3;
    float rx = pn[0]-pc[0], ry = pn[1]-pc[1], rz = pn[2]-pc[2];
    #pragma unroll
    for (int j = 0; j < H_; ++j){
        float a = fmaf(rx, W1[j], fmaf(ry, W1[H_+j], fmaf(rz, W1[2*H_+j], b1[j])));
        h1[j] = fmaxf(a, 0.0f);
    }
}

__device__ __forceinline__ void mlp12(const float* __restrict__ xyz, const int* __restrict__ idx, int r,
                                      const float* __restrict__ W1, const float* __restrict__ b1,
                                      const float* __restrict__ a1, const float* __restrict__ bb1,
                                      const float* __restrict__ W2, const float* __restrict__ b2, float* h2){
    float h1[H_];
    compute_h1(xyz, idx, r, W1, b1, h1);
    #pragma unroll
    for (int j = 0; j < H_; ++j) h1[j] = fmaf(a1[j], h1[j], bb1[j]);
    #pragma unroll
    for (int j = 0; j < H_; ++j) h2[j] = b2[j];
    #pragma unroll 4
    for (int hh = 0; hh < H_; ++hh){
        float c = h1[hh];
        #pragma unroll
        for (int j = 0; j < H_; ++j) h2[j] = fmaf(c, W2[hh*H_+j], h2[j]);
    }
    #pragma unroll
    for (int j = 0; j < H_; ++j) h2[j] = fmaxf(h2[j], 0.0f);
}

// block-level per-channel sum/sumsq -> 64 global atomics per block
#define TSTRIDE 33
__device__ __forceinline__ void block_stats(float* tile /*256*33*/, const float* h,
                                            float* __restrict__ gsum, float* __restrict__ gsq){
    int tid = threadIdx.x;
    #pragma unroll
    for (int j = 0; j < H_; ++j) tile[tid*TSTRIDE + j] = h[j];
    __syncthreads();
    int cho = tid & 31, chunk = tid >> 5;
    float s = 0.f, q = 0.f;
    #pragma unroll
    for (int rr = 0; rr < 32; ++rr){
        float v = tile[(chunk*32 + rr)*TSTRIDE + cho];
        s += v; q = fmaf(v, v, q);
    }
    __syncthreads();
    tile[tid] = s; tile[256 + tid] = q;
    __syncthreads();
    if (tid < 32){
        float ss = 0.f, qq = 0.f;
        #pragma unroll
        for (int g = 0; g < 8; ++g){ ss += tile[g*32 + tid]; qq += tile[256 + g*32 + tid]; }
        atomicAdd(&gsum[tid], ss);
        atomicAdd(&gsq[tid], qq);
    }
}

__global__ __launch_bounds__(256) void k_h1stats(const float* __restrict__ xyz, const int* __restrict__ idx,
                                                 const float* __restrict__ W1, const float* __restrict__ b1,
                                                 float* gsum, float* gsq){
    __shared__ float tile[256*TSTRIDE];
    int r = blockIdx.x*256 + threadIdx.x;
    float h1[H_];
    compute_h1(xyz, idx, r, W1, b1, h1);
    block_stats(tile, h1, gsum, gsq);
}

__global__ __launch_bounds__(256) void k_h2stats(const float* __restrict__ xyz, const int* __restrict__ idx,
                                                 const float* __restrict__ W1, const float* __restrict__ b1,
                                                 const float* __restrict__ a1, const float* __restrict__ bb1,
                                                 const float* __restrict__ W2, const float* __restrict__ b2,
                                                 float* gsum, float* gsq){
    __shared__ float tile[256*TSTRIDE];
    int r = blockIdx.x*256 + threadIdx.x;
    float h2[H_];
    mlp12(xyz, idx, r, W1, b1, a1, bb1, W2, b2, h2);
    block_stats(tile, h2, gsum, gsq);
}

__global__ void k_fin(const float* gsum, const float* gsq, const float* __restrict__ g,
                      const float* __restrict__ be, float invn, float* a, float* bb){
    int j = threadIdx.x;
    if (j < 32){
        float m = gsum[j] * invn;
        float v = gsq[j] * invn - m*m;
        float aj = g[j] / sqrtf(v + EPS_);
        a[j] = aj;
        bb[j] = fmaf(-aj, m, be[j]);
    }
}

// ---- prep: W3(f32) -> bf16 fragment-ordered Bl (K extended to 544 to fold gp.b3); zero stats ----
__global__ __launch_bounds__(256) void k_prep(const float* __restrict__ W3, const float* __restrict__ b3,
                                              unsigned short* __restrict__ Blg, float* __restrict__ st){
    int flat = blockIdx.x*256 + threadIdx.x;
    if (flat < 17408){
        int j   = flat & 7;
        int col = (flat >> 3) & 31;
        int q   = (flat >> 8) & 3;
        int kb  = flat >> 10;
        int k   = kb*32 + q*8 + j;
        float val;
        if (k < 512) val = W3[(k >> 4)*512 + (k & 15)*32 + col];
        else { int c = k - 512; val = (c < 16) ? b3[c*32 + col] : 0.0f; }
        Blg[flat] = f2bf_rne(val);
    }
    if (blockIdx.x == 0){
        for (int i = threadIdx.x; i < 384; i += 256) st[i] = 0.f;
    }
}

// ---------------- main fused stage: mlp12 -> BN2(streamed) -> bf16 MFMA (K=544) -> max over k ----------------
// __launch_bounds__(256,2): (256,4) caps VGPR at 64 -> scratch spill (round-2 lesson)
__global__ __launch_bounds__(256,2) void k_out(const float* __restrict__ xyz, const float* __restrict__ points,
                                               const int* __restrict__ idx,
                                               const float* __restrict__ W1, const float* __restrict__ b1,
                                               const float* __restrict__ a1, const float* __restrict__ bb1,
                                               const float* __restrict__ W2, const float* __restrict__ b2,
                                               const float* __restrict__ s2, const float* __restrict__ q2,
                                               const float* __restrict__ g2, const float* __restrict__ be2,
                                               const unsigned short* __restrict__ Blg,
                                               float* __restrict__ out_pre, float* gsum, float* gsq){
    __shared__ uint4 Bls[2176];        // 34816 B: bf16 B-fragments, 17 kb-steps x 4 q x 32 cols x 8
    __shared__ float redS[COUT_], redQ[COUT_];
    int tid = threadIdx.x;
    for (int i = tid; i < 2176; i += 256) Bls[i] = ((const uint4*)Blg)[i];
    if (tid < COUT_){ redS[tid] = 0.f; redQ[tid] = 0.f; }
    __syncthreads();

    int r = blockIdx.x*256 + tid;
    int b = r >> 16;
    int id = idx[r];

    float h2n[H_];
    mlp12(xyz, idx, r, W1, b1, a1, bb1, W2, b2, h2n);
    // BN2 applied streamed: s2/q2/g2/be2 are uniform s_loads, scale computed and consumed per j
    #pragma unroll
    for (int h = 0; h < H_; ++h){
        float mm = s2[h] * INVR_;
        float vv = q2[h] * INVR_ - mm*mm;
        float aa = g2[h] / sqrtf(vv + EPS_);
        h2n[h] = fmaf(aa, h2n[h], fmaf(-aa, mm, be2[h]));
    }

    float gp[CIN_];
    const float4* pp = (const float4*)(points + ((size_t)b*N_ + id)*CIN_);
    #pragma unroll
    for (int c4 = 0; c4 < CIN_/4; ++c4){
        float4 v = pp[c4];
        gp[4*c4] = v.x; gp[4*c4+1] = v.y; gp[4*c4+2] = v.z; gp[4*c4+3] = v.w;
    }

    const int lane = tid & 63;
    const int w    = tid >> 6;
    const int q    = lane >> 4;
    const int m    = lane & 15;

    #pragma unroll
    for (int p = 0; p < 2; ++p){           // two (b,n)-groups of 32 rows per wave
        float pv0 = -3.4e38f, pv1 = -3.4e38f;
        #pragma unroll
        for (int tp = 0; tp < 2; ++tp){    // two 16-row MFMA tiles per group
            const int tile = p*2 + tp;
            const int src  = tile*16 + m;  // source lane holding this tile-row's h2n/gp
            float gpr[8];
            #pragma unroll
            for (int j = 0; j < 8; ++j){
                float lo = __shfl(gp[j],     src, 64);
                float hi = __shfl(gp[8 + j], src, 64);
                gpr[j] = (q & 1) ? hi : lo;
            }
            f32x4 acc0 = {0.f,0.f,0.f,0.f}, acc1 = {0.f,0.f,0.f,0.f};
            #pragma unroll
            for (int kb = 0; kb < 17; ++kb){
                float hv;
                if (kb < 16){
                    float he = __shfl(h2n[2*kb],     src, 64);
                    float ho = __shfl(h2n[2*kb + 1], src, 64);
                    hv = (q >> 1) ? ho : he;
                } else {
                    hv = (q < 2) ? 1.0f : 0.0f;     // b3 fold: v[512+c] = gp[c]
                }
                union { unsigned int u[4]; short8 s8; } af;
                #pragma unroll
                for (int jj = 0; jj < 4; ++jj){
                    float p0 = hv * gpr[2*jj];
                    float p1 = hv * gpr[2*jj + 1];
                    af.u[jj] = __builtin_amdgcn_perm(__float_as_uint(p1), __float_as_uint(p0), 0x07060302u);
                }
                union { uint4 u4; short8 s8; } bf0, bf1;
                bf0.u4 = Bls[(kb*4 + q)*32 + m];
                bf1.u4 = Bls[(kb*4 + q)*32 + 16 + m];
                acc0 = __builtin_amdgcn_mfma_f32_16x16x32_bf16(af.s8, bf0.s8, acc0, 0, 0, 0);
                acc1 = __builtin_amdgcn_mfma_f32_16x16x32_bf16(af.s8, bf1.s8, acc1, 0, 0, 0);
            }
            float v0 = fmaxf(fmaxf(acc0[0], acc0[1]), fmaxf(acc0[2], acc0[3]));
            float v1 = fmaxf(fmaxf(acc1[0], acc1[1]), fmaxf(acc1[2], acc1[3]));
            pv0 = fmaxf(pv0, v0);
            pv1 = fmaxf(pv1, v1);
        }
        pv0 = fmaxf(pv0, __shfl_xor(pv0, 16, 64));
        pv0 = fmaxf(pv0, __shfl_xor(pv0, 32, 64));
        pv1 = fmaxf(pv1, __shfl_xor(pv1, 16, 64));
        pv1 = fmaxf(pv1, __shfl_xor(pv1, 32, 64));
        if (lane < 32){
            float v = (lane < 16) ? pv0 : pv1;     // lane l -> output channel l
            int g = blockIdx.x*8 + w*2 + p;        // (b,n) group id
            out_pre[(size_t)g*COUT_ + lane] = v;
            atomicAdd(&redS[lane], v);
            atomicAdd(&redQ[lane], v*v);
        }
    }
    __syncthreads();
    if (tid < COUT_){
        atomicAdd(&gsum[tid], redS[tid]);
        atomicAdd(&gsq[tid],  redQ[tid]);
    }
}

// final BN: per-thread single-channel scale computed inline (k_fin fold)
__global__ __launch_bounds__(256) void k_bn(const float* __restrict__ out_pre,
                                            const float* __restrict__ s3, const float* __restrict__ q3,
                                            const float* __restrict__ gbn, const float* __restrict__ bbn,
                                            float* __restrict__ out){
    int i = blockIdx.x*256 + threadIdx.x;
    int o = i & (COUT_-1);
    float mm = s3[o] * INVBN_;
    float vv = q3[o] * INVBN_ - mm*mm;
    float aa = gbn[o] / sqrtf(vv + EPS_);
    out[i] = fmaf(aa, out_pre[i], fmaf(-aa, mm, bbn[o]));
}

extern "C" void kernel_launch(void* const* d_in, const int* in_sizes, int n_in,
                              void* d_out, int out_size, void* d_ws, size_t ws_size,
                              hipStream_t stream){
    const float* xyz    = (const float*)d_in[0];
    const float* points = (const float*)d_in[1];
    const float* W1  = (const float*)d_in[2];
    const float* b1  = (const float*)d_in[3];
    const float* g1  = (const float*)d_in[4];
    const float* be1 = (const float*)d_in[5];
    const float* W2  = (const float*)d_in[6];
    const float* b2  = (const float*)d_in[7];
    const float* g2  = (const float*)d_in[8];
    const float* be2 = (const float*)d_in[9];
    const float* W3  = (const float*)d_in[10];
    const float* b3  = (const float*)d_in[11];
    const float* gbn = (const float*)d_in[12];
    const float* bbn = (const float*)d_in[13];
    float* out = (float*)d_out;

    // ws layout (floats): idx[R_] | out_pre[B_*N_*COUT_] | st[384] | Bl bf16[17408]
    int*   idx     = (int*)d_ws;
    float* out_pre = (float*)d_ws + R_;
    float* st      = out_pre + (size_t)B_*N_*COUT_;
    unsigned short* Blg = (unsigned short*)(st + 384);
    float *s1=st, *q1=st+32, *s2=st+64, *q2=st+96, *s3=st+128, *q3=st+160;
    float *a1=st+192, *bb1=st+224;

    hipLaunchKernelGGL(k_prep,    dim3(68),            dim3(256), 0, stream, W3, b3, Blg, st);
    hipLaunchKernelGGL(k_knn,     dim3(B_*(N_/QPB)),   dim3(256), 0, stream, xyz, idx);
    hipLaunchKernelGGL(k_h1stats, dim3(R_/256),        dim3(256), 0, stream, xyz, idx, W1, b1, s1, q1);
    hipLaunchKernelGGL(k_fin,     dim3(1),             dim3(64),  0, stream, s1, q1, g1, be1, INVR_, a1, bb1);
    hipLaunchKernelGGL(k_h2stats, dim3(R_/256),        dim3(256), 0, stream, xyz, idx, W1, b1, a1, bb1, W2, b2, s2, q2);
    hipLaunchKernelGGL(k_out,     dim3(R_/256),        dim3(256), 0, stream, xyz, points, idx, W1, b1, a1, bb1,
                       W2, b2, s2, q2, g2, be2, Blg, out_pre, s3, q3);
    hipLaunchKernelGGL(k_bn,      dim3(B_*N_*COUT_/256), dim3(256), 0, stream, out_pre, s3, q3, gbn, bbn, out);
}

// Round 6
// 196.105 us; speedup vs baseline: 2.4390x; 1.1753x over previous
//
#include <hip/hip_runtime.h>

#define B_ 4
#define N_ 2048
#define K_ 32
#define CIN_ 16
#define COUT_ 32
#define H_ 32
#define R_ (B_*N_*K_)      // 262144 rows through the weight-net
#define EPS_ 1e-5f
#define INVR_ (1.0f/(float)R_)
#define INVBN_ (1.0f/(float)(B_*N_))
#define QPB 4              // queries (waves) per block in knn
#define LISTCAP 384

typedef __attribute__((ext_vector_type(8)))  _Float16 f16x8;
typedef __attribute__((ext_vector_type(2)))  __fp16   hw16x2;   // builtin cvt_pkrtz return type
typedef __attribute__((ext_vector_type(2)))  _Float16 f16x2;
typedef __attribute__((ext_vector_type(16))) float    f32x16;

__device__ __forceinline__ float dot3f(float ax,float ay,float az,float bx,float by,float bz){
    return fmaf(az,bz, fmaf(ay,by, ax*bx));
}
__device__ __forceinline__ unsigned int flip_f32(float d){
    unsigned int u = __float_as_uint(d);
    return u ^ ((unsigned int)(((int)u) >> 31) | 0x80000000u);
}
__device__ __forceinline__ unsigned int pk2(float a, float b){   // packed f16 pair (RTZ)
    union { hw16x2 v; unsigned int u; } c;
    c.v = __builtin_amdgcn_cvt_pkrtz(a, b);
    return c.u;
}
__device__ __forceinline__ unsigned int pkmul(unsigned int a, unsigned int b){  // v_pk_mul_f16
    union { unsigned int u; f16x2 v; } x, y, r;
    x.u = a; y.u = b; r.v = x.v * y.v; return r.u;
}

// wave-local histogram select
__device__ __forceinline__ void hsel(const unsigned int* hw, int lane,
                                     unsigned int Kthr, int* Bsel, unsigned int* below){
    uint4 ha = ((const uint4*)hw)[2*lane];
    uint4 hb = ((const uint4*)hw)[2*lane+1];
    unsigned int g0 = ha.x+ha.y, g1 = ha.z+ha.w, g2 = hb.x+hb.y, g3 = hb.z+hb.w;
    unsigned int gs = g0+g1+g2+g3, cum = gs;
    #pragma unroll
    for (int off = 1; off < 64; off <<= 1){
        unsigned int v = __shfl_up(cum, off);
        if (lane >= off) cum += v;
    }
    unsigned long long bal = __ballot(cum >= Kthr);
    int L = __ffsll(bal) - 1;
    unsigned int run = __shfl(cum, L) - __shfl(gs, L);
    unsigned int h0 = __shfl(g0, L), h1 = __shfl(g1, L), h2 = __shfl(g2, L);
    if      (run + h0 >= Kthr)           { *Bsel = 4*L;     *below = run; }
    else if (run + h0 + h1 >= Kthr)      { *Bsel = 4*L + 1; *below = run + h0; }
    else if (run + h0 + h1 + h2 >= Kthr) { *Bsel = 4*L + 2; *below = run + h0 + h1; }
    else                                 { *Bsel = 4*L + 3; *below = run + h0 + h1 + h2; }
}

// ---------------- KNN (two-level radix) + zero stats ----------------
__global__ __launch_bounds__(256) void k_knn(const float* __restrict__ xyz, int* __restrict__ idx_out,
                                             float* __restrict__ st){
    __shared__ float4 xs4[N_];
    __shared__ unsigned int hist[QPB][256][2];
    __shared__ unsigned long long lst[QPB][LISTCAP];

    const int tid  = threadIdx.x;
    const int w    = tid >> 6;
    const int lane = tid & 63;
    const int b    = blockIdx.x / (N_/QPB);
    const int q    = (blockIdx.x % (N_/QPB)) * QPB + w;

    if (blockIdx.x == 0 && tid < 192) st[tid] = 0.f;

    const float* xb = xyz + (size_t)b * N_ * 3;
    for (int i = tid; i < N_; i += 256){
        float x = xb[3*i], y = xb[3*i+1], z = xb[3*i+2];
        xs4[i] = make_float4(x, y, z, dot3f(x,y,z,x,y,z));
    }
    for (int i = lane; i < 512; i += 64) ((unsigned int*)hist[w])[i] = 0u;
    __syncthreads();

    const float4 qp = xs4[q];
    const float qx = qp.x, qy = qp.y, qz = qp.z, sqq = qp.w;

    unsigned int fv[32];
    #pragma unroll
    for (int j = 0; j < 32; ++j){
        int c = j*64 + lane;
        float4 pt = xs4[c];
        float d = fmaf(-2.0f, dot3f(qx,qy,qz, pt.x,pt.y,pt.z), sqq) + pt.w;
        unsigned int f = flip_f32(d);
        fv[j] = f;
        atomicAdd(&hist[w][f >> 24][lane & 1], 1u);
    }
    int B0; unsigned int lt0;
    hsel(&hist[w][0][0], lane, (unsigned)K_, &B0, &lt0);
    unsigned int Kp = (unsigned)K_ - lt0;

    for (int i = lane; i < 512; i += 64) ((unsigned int*)hist[w])[i] = 0u;
    #pragma unroll
    for (int j = 0; j < 32; ++j){
        if ((int)(fv[j] >> 24) == B0)
            atomicAdd(&hist[w][(fv[j] >> 16) & 0xFF][lane & 1], 1u);
    }
    int B1; unsigned int lt1;
    hsel(&hist[w][0][0], lane, Kp, &B1, &lt1);

    const unsigned long long mlt = (lane == 63) ? ~0ull >> 1 : (1ull << lane) - 1ull;
    unsigned int cnt = 0;
    #pragma unroll
    for (int j = 0; j < 32; ++j){
        unsigned int f = fv[j];
        int top = (int)(f >> 24);
        bool surv = (top < B0) || (top == B0 && (int)((f >> 16) & 0xFF) <= B1);
        unsigned long long sb = __ballot(surv);
        unsigned int pos = cnt + (unsigned int)__popcll(sb & mlt);
        if (surv && pos < (unsigned)LISTCAP)
            lst[w][pos] = ((unsigned long long)f << 32) | (unsigned int)(j*64 + lane);
        cnt += (unsigned int)__popcll(sb);
    }
    int m = (int)cnt; if (m > LISTCAP) m = LISTCAP;

    int* outp = idx_out + ((size_t)b * N_ + q) * K_;
    for (int i = lane; i < m; i += 64){
        unsigned long long my = lst[w][i];
        int rank = 0;
        for (int jj = 0; jj < m; ++jj)
            rank += (lst[w][jj] < my) ? 1 : 0;
        if (rank < K_) outp[rank] = (int)(unsigned int)(my & 0xFFFFFFFFull);
    }
}

// ---------------- h1 (raw) ----------------
__device__ __forceinline__ void compute_h1(const float* __restrict__ xyz, const int* __restrict__ idx, int r,
                                           const float* __restrict__ W1, const float* __restrict__ b1, float* h1){
    int b = r >> 16;
    int n = (r >> 5) & (N_-1);
    int id = idx[r];
    const float* pc = xyz + ((size_t)b*N_ + n)*3;
    const float* pn = xyz + ((size_t)b*N_ + id)*3;
    float rx = pn[0]-pc[0], ry = pn[1]-pc[1], rz = pn[2]-pc[2];
    #pragma unroll
    for (int j = 0; j < H_; ++j){
        float a = fmaf(rx, W1[j], fmaf(ry, W1[H_+j], fmaf(rz, W1[2*H_+j], b1[j])));
        h1[j] = fmaxf(a, 0.0f);
    }
}

#define TSTRIDE 33
__global__ __launch_bounds__(256) void k_h1stats(const float* __restrict__ xyz, const int* __restrict__ idx,
                                                 const float* __restrict__ W1, const float* __restrict__ b1,
                                                 float* gsum, float* gsq){
    __shared__ float tile[256*TSTRIDE];
    int tid = threadIdx.x;
    int r = blockIdx.x*256 + tid;
    float h1[H_];
    compute_h1(xyz, idx, r, W1, b1, h1);
    #pragma unroll
    for (int j = 0; j < H_; ++j) tile[tid*TSTRIDE + j] = h1[j];
    __syncthreads();
    int cho = tid & 31, chunk = tid >> 5;
    float s = 0.f, q = 0.f;
    #pragma unroll
    for (int rr = 0; rr < 32; ++rr){
        float v = tile[(chunk*32 + rr)*TSTRIDE + cho];
        s += v; q = fmaf(v, v, q);
    }
    __syncthreads();
    tile[tid] = s; tile[256 + tid] = q;
    __syncthreads();
    if (tid < 32){
        float ss = 0.f, qq = 0.f;
        #pragma unroll
        for (int g = 0; g < 8; ++g){ ss += tile[g*32 + tid]; qq += tile[256 + g*32 + tid]; }
        atomicAdd(&gsum[tid], ss);
        atomicAdd(&gsq[tid], qq);
    }
}

// ---- prep2: points->f16 pairs; W2' = a1(.)W2 f16 B-frags; b2' = b2 + bb1@W2 ----
__global__ __launch_bounds__(256) void k_prep2(const float* __restrict__ points,
                                               const float* __restrict__ s1, const float* __restrict__ q1,
                                               const float* __restrict__ g1, const float* __restrict__ be1,
                                               const float* __restrict__ W2, const float* __restrict__ b2,
                                               unsigned int* __restrict__ pf16, unsigned int* __restrict__ W2f,
                                               float* __restrict__ b2p){
    int flat = blockIdx.x*256 + threadIdx.x;
    if (flat < 65536){
        pf16[flat] = pk2(points[2*flat], points[2*flat+1]);
    } else if (flat < 66048){
        int d = flat - 65536;              // W2f dword index = (step*64+lane)*4+jj
        int jj = d & 3, lane = (d >> 2) & 63, step = d >> 8;
        int col = lane & 31;
        int k0 = step*16 + (lane >> 5)*8 + 2*jj;
        float m0 = s1[k0]*INVR_,   v0 = q1[k0]*INVR_   - m0*m0;
        float m1 = s1[k0+1]*INVR_, v1 = q1[k0+1]*INVR_ - m1*m1;
        float a0 = g1[k0]   / sqrtf(v0 + EPS_);
        float a1v = g1[k0+1] / sqrtf(v1 + EPS_);
        W2f[d] = pk2(a0*W2[k0*H_ + col], a1v*W2[(k0+1)*H_ + col]);
    } else if (flat < 66080){
        int col = flat - 66048;
        float acc = b2[col];
        #pragma unroll 4
        for (int h = 0; h < H_; ++h){
            float mm = s1[h]*INVR_, vv = q1[h]*INVR_ - mm*mm;
            float aa = g1[h] / sqrtf(vv + EPS_);
            float bb = fmaf(-aa, mm, be1[h]);
            acc = fmaf(bb, W2[h*H_ + col], acc);
        }
        b2p[col] = acc;
    }
}

// ---- k_h2: h1 scalar -> layer2 via MFMA 32x32x16 f16 (bias via C-init) -> raw h2 f16 + stats ----
__global__ __launch_bounds__(256,3) void k_h2(const float* __restrict__ xyz, const int* __restrict__ idx,
                                              const float* __restrict__ W1, const float* __restrict__ b1,
                                              const uint4* __restrict__ W2f, const float* __restrict__ b2p,
                                              unsigned short* __restrict__ h2g,
                                              float* gsum, float* gsq){
    __shared__ float redS[H_], redQ[H_];
    const int tid = threadIdx.x, lane = tid & 63, w = tid >> 6;
    const int half = lane >> 5, m = lane & 31;
    if (tid < H_){ redS[tid] = 0.f; redQ[tid] = 0.f; }
    __syncthreads();

    int r = blockIdx.x*256 + tid;
    float h1[H_];
    compute_h1(xyz, idx, r, W1, b1, h1);
    unsigned int h1p[16];
    #pragma unroll
    for (int i = 0; i < 16; ++i) h1p[i] = pk2(h1[2*i], h1[2*i+1]);

    union { uint4 u4; f16x8 v; } Bf0, Bf1;
    Bf0.u4 = W2f[lane];
    Bf1.u4 = W2f[64 + lane];
    float b2c = b2p[m];

    const int rB = blockIdx.x*256 + w*64;
    float s = 0.f, q = 0.f;
    #pragma unroll
    for (int t = 0; t < 2; ++t){
        const int src = t*32 + m;
        union { unsigned int u[4]; f16x8 v; } a0, a1f;
        #pragma unroll
        for (int jj = 0; jj < 4; ++jj){
            unsigned int lo = __shfl(h1p[jj],     src, 64);
            unsigned int hi = __shfl(h1p[4 + jj], src, 64);
            a0.u[jj] = half ? hi : lo;
        }
        #pragma unroll
        for (int jj = 0; jj < 4; ++jj){
            unsigned int lo = __shfl(h1p[8 + jj],  src, 64);
            unsigned int hi = __shfl(h1p[12 + jj], src, 64);
            a1f.u[jj] = half ? hi : lo;
        }
        f32x16 acc;
        #pragma unroll
        for (int i = 0; i < 16; ++i) acc[i] = b2c;
        acc = __builtin_amdgcn_mfma_f32_32x32x16_f16(a0.v,  Bf0.v, acc, 0, 0, 0);
        acc = __builtin_amdgcn_mfma_f32_32x32x16_f16(a1f.v, Bf1.v, acc, 0, 0, 0);
        #pragma unroll
        for (int i = 0; i < 16; ++i){
            float v = fmaxf(acc[i], 0.0f);
            int row = rB + t*32 + (i & 3) + 8*(i >> 2) + 4*half;
            union { _Float16 h; unsigned short u; } cv; cv.h = (_Float16)v;
            h2g[(size_t)row*H_ + m] = cv.u;
            s += v; q = fmaf(v, v, q);
        }
    }
    s += __shfl_xor(s, 32, 64);
    q += __shfl_xor(q, 32, 64);
    if (lane < 32){ atomicAdd(&redS[m], s); atomicAdd(&redQ[m], q); }
    __syncthreads();
    if (tid < H_){ atomicAdd(&gsum[tid], redS[tid]); atomicAdd(&gsq[tid], redQ[tid]); }
}

// ---- prep3: W3'' = aa2(.)W3 (+ b3' bias row at step 32) -> f16 B-frags for K=528 ----
__global__ __launch_bounds__(256) void k_prep3(const float* __restrict__ W3, const float* __restrict__ b3,
                                               const float* __restrict__ s2, const float* __restrict__ q2,
                                               const float* __restrict__ g2, const float* __restrict__ be2,
                                               unsigned int* __restrict__ W3f){
    int d = blockIdx.x*256 + threadIdx.x;     // 33*256 = 8448 dwords
    int jj = d & 3, lane = (d >> 2) & 63, step = d >> 8;
    int col = lane & 31;
    int off = (lane >> 5)*8 + 2*jj;
    float v0, v1;
    if (step < 32){
        int h = step, c0 = off;
        float mm = s2[h]*INVR_, vv = q2[h]*INVR_ - mm*mm;
        float aa = g2[h] / sqrtf(vv + EPS_);
        v0 = aa * W3[h*512 + c0*COUT_ + col];
        v1 = aa * W3[h*512 + (c0+1)*COUT_ + col];
    } else {
        int c0 = off;
        v0 = b3[c0*COUT_ + col]; v1 = b3[(c0+1)*COUT_ + col];
        #pragma unroll 4
        for (int h = 0; h < H_; ++h){
            float mm = s2[h]*INVR_, vv = q2[h]*INVR_ - mm*mm;
            float aa = g2[h] / sqrtf(vv + EPS_);
            float bb = fmaf(-aa, mm, be2[h]);
            v0 = fmaf(bb, W3[h*512 + c0*COUT_ + col], v0);
            v1 = fmaf(bb, W3[h*512 + (c0+1)*COUT_ + col], v1);
        }
    }
    W3f[d] = pk2(v0, v1);
}

// ---- k_out: A = outer(h2,gp) built f16-packed from memory; 33-step MFMA 32x32x16; max over k ----
__global__ __launch_bounds__(256,3) void k_out(const int* __restrict__ idx,
                                               const unsigned int* __restrict__ pf16,
                                               const unsigned int* __restrict__ h2u,
                                               const uint4* __restrict__ W3f,
                                               float* __restrict__ out_pre, float* gsum, float* gsq){
    __shared__ float redS[COUT_], redQ[COUT_];
    const int tid = threadIdx.x, lane = tid & 63, w = tid >> 6;
    const int half = lane >> 5, m = lane & 31;
    if (tid < COUT_){ redS[tid] = 0.f; redQ[tid] = 0.f; }
    __syncthreads();

    const int rB = blockIdx.x*256 + w*64;
    const uint4* Wf = W3f + lane;

    #pragma unroll
    for (int t = 0; t < 2; ++t){
        int row = rB + t*32 + m;
        int b = row >> 16;
        int id = idx[row];
        const uint4* gpp = (const uint4*)(pf16 + ((size_t)b*N_ + id)*8);
        uint4 ga = gpp[0], gb = gpp[1];
        unsigned int gsel[4];
        gsel[0] = half ? gb.x : ga.x;
        gsel[1] = half ? gb.y : ga.y;
        gsel[2] = half ? gb.z : ga.z;
        gsel[3] = half ? gb.w : ga.w;
        const uint4* hp = (const uint4*)(h2u + (size_t)row*16);
        uint4 hA = hp[0], hB = hp[1], hC = hp[2], hD = hp[3];
        unsigned int h2p[16] = {hA.x,hA.y,hA.z,hA.w, hB.x,hB.y,hB.z,hB.w,
                                hC.x,hC.y,hC.z,hC.w, hD.x,hD.y,hD.z,hD.w};
        f32x16 acc;
        #pragma unroll
        for (int i = 0; i < 16; ++i) acc[i] = 0.f;

        #pragma unroll
        for (int kb = 0; kb < 32; ++kb){
            unsigned int hr = h2p[kb >> 1];
            unsigned int hd = __builtin_amdgcn_perm(hr, hr, (kb & 1) ? 0x03020302u : 0x01000100u);
            union { unsigned int u[4]; f16x8 v; } af;
            #pragma unroll
            for (int jj = 0; jj < 4; ++jj) af.u[jj] = pkmul(hd, gsel[jj]);
            union { uint4 u4; f16x8 v; } bf; bf.u4 = Wf[kb*64];
            acc = __builtin_amdgcn_mfma_f32_32x32x16_f16(af.v, bf.v, acc, 0, 0, 0);
        }
        {   // bias step: A = gp, B = b3'
            union { unsigned int u[4]; f16x8 v; } af;
            #pragma unroll
            for (int jj = 0; jj < 4; ++jj) af.u[jj] = gsel[jj];
            union { uint4 u4; f16x8 v; } bf; bf.u4 = Wf[32*64];
            acc = __builtin_amdgcn_mfma_f32_32x32x16_f16(af.v, bf.v, acc, 0, 0, 0);
        }

        float v = acc[0];
        #pragma unroll
        for (int i = 1; i < 16; ++i) v = fmaxf(v, acc[i]);
        v = fmaxf(v, __shfl_xor(v, 32, 64));
        if (lane < 32){
            int g = blockIdx.x*8 + w*2 + t;
            out_pre[(size_t)g*COUT_ + m] = v;
            atomicAdd(&redS[m], v);
            atomicAdd(&redQ[m], v*v);
        }
    }
    __syncthreads();
    if (tid < COUT_){ atomicAdd(&gsum[tid], redS[tid]); atomicAdd(&gsq[tid], redQ[tid]); }
}

__global__ __launch_bounds__(256) void k_bn(const float* __restrict__ out_pre,
                                            const float* __restrict__ s3, const float* __restrict__ q3,
                                            const float* __restrict__ gbn, const float* __restrict__ bbn,
                                            float* __restrict__ out){
    int i = blockIdx.x*256 + threadIdx.x;
    int o = i & (COUT_-1);
    float mm = s3[o] * INVBN_;
    float vv = q3[o] * INVBN_ - mm*mm;
    float aa = gbn[o] / sqrtf(vv + EPS_);
    out[i] = fmaf(aa, out_pre[i], fmaf(-aa, mm, bbn[o]));
}

extern "C" void kernel_launch(void* const* d_in, const int* in_sizes, int n_in,
                              void* d_out, int out_size, void* d_ws, size_t ws_size,
                              hipStream_t stream){
    const float* xyz    = (const float*)d_in[0];
    const float* points = (const float*)d_in[1];
    const float* W1  = (const float*)d_in[2];
    const float* b1  = (const float*)d_in[3];
    const float* g1  = (const float*)d_in[4];
    const float* be1 = (const float*)d_in[5];
    const float* W2  = (const float*)d_in[6];
    const float* b2  = (const float*)d_in[7];
    const float* g2  = (const float*)d_in[8];
    const float* be2 = (const float*)d_in[9];
    const float* W3  = (const float*)d_in[10];
    const float* b3  = (const float*)d_in[11];
    const float* gbn = (const float*)d_in[12];
    const float* bbn = (const float*)d_in[13];
    float* out = (float*)d_out;

    // ws layout (bytes):
    char* base = (char*)d_ws;
    int*            idx     = (int*)(base + 0);                     // 1,048,576
    float*          out_pre = (float*)(base + 1048576);             // 1,048,576
    unsigned short* h2g     = (unsigned short*)(base + 2097152);    // 16,777,216
    unsigned int*   pf16    = (unsigned int*)(base + 18874368);     //    262,144
    unsigned int*   W3f     = (unsigned int*)(base + 19136512);     //     33,792
    unsigned int*   W2f     = (unsigned int*)(base + 19170304);     //      2,048
    float*          b2p     = (float*)(base + 19172352);            //        128
    float*          st      = (float*)(base + 19172480);            //        768
    float *s1=st, *q1=st+32, *s2=st+64, *q2=st+96, *s3=st+128, *q3=st+160;

    hipLaunchKernelGGL(k_knn,     dim3(B_*(N_/QPB)), dim3(256), 0, stream, xyz, idx, st);
    hipLaunchKernelGGL(k_h1stats, dim3(R_/256),      dim3(256), 0, stream, xyz, idx, W1, b1, s1, q1);
    hipLaunchKernelGGL(k_prep2,   dim3(260),         dim3(256), 0, stream, points, s1, q1, g1, be1, W2, b2,
                       pf16, W2f, b2p);
    hipLaunchKernelGGL(k_h2,      dim3(R_/256),      dim3(256), 0, stream, xyz, idx, W1, b1,
                       (const uint4*)W2f, b2p, h2g, s2, q2);
    hipLaunchKernelGGL(k_prep3,   dim3(33),          dim3(256), 0, stream, W3, b3, s2, q2, g2, be2, W3f);
    hipLaunchKernelGGL(k_out,     dim3(R_/256),      dim3(256), 0, stream, idx, pf16, (const unsigned int*)h2g,
                       (const uint4*)W3f, out_pre, s3, q3);
    hipLaunchKernelGGL(k_bn,      dim3(B_*N_*COUT_/256), dim3(256), 0, stream, out_pre, s3, q3, gbn, bbn, out);
}

// Round 7
// 186.855 us; speedup vs baseline: 2.5597x; 1.0495x over previous
//
#include <hip/hip_runtime.h>

#define B_ 4
#define N_ 2048
#define K_ 32
#define CIN_ 16
#define COUT_ 32
#define H_ 32
#define R_ (B_*N_*K_)      // 262144 rows through the weight-net
#define EPS_ 1e-5f
#define INVR_ (1.0f/(float)R_)
#define INVBN_ (1.0f/(float)(B_*N_))
#define LISTCAP 192

typedef __attribute__((ext_vector_type(8)))  _Float16 f16x8;
typedef __attribute__((ext_vector_type(2)))  __fp16   hw16x2;   // builtin cvt_pkrtz return type
typedef __attribute__((ext_vector_type(2)))  _Float16 f16x2;
typedef __attribute__((ext_vector_type(16))) float    f32x16;

__device__ __forceinline__ float dot3f(float ax,float ay,float az,float bx,float by,float bz){
    return fmaf(az,bz, fmaf(ay,by, ax*bx));
}
__device__ __forceinline__ unsigned int flip_f32(float d){
    unsigned int u = __float_as_uint(d);
    return u ^ ((unsigned int)(((int)u) >> 31) | 0x80000000u);
}
__device__ __forceinline__ unsigned int pk2(float a, float b){   // packed f16 pair (RTZ)
    union { hw16x2 v; unsigned int u; } c;
    c.v = __builtin_amdgcn_cvt_pkrtz(a, b);
    return c.u;
}
__device__ __forceinline__ unsigned int pkmul(unsigned int a, unsigned int b){  // v_pk_mul_f16
    union { unsigned int u; f16x2 v; } x, y, r;
    x.u = a; y.u = b; r.v = x.v * y.v; return r.u;
}
// sum of 8 shadow accumulators
__device__ __forceinline__ float sh8(const float* __restrict__ p, int k){
    float s = 0.f;
    #pragma unroll
    for (int i = 0; i < 8; ++i) s += p[i*32 + k];
    return s;
}

// wave hist select over 4-replica histogram: smallest bucket with cumulative >= Kthr
__device__ __forceinline__ void hsel4(const unsigned int* hq /*256 buckets x4 replicas*/, int lane,
                                      unsigned int Kthr, int* Bsel, unsigned int* below){
    unsigned int g[4];
    #pragma unroll
    for (int t = 0; t < 4; ++t){
        uint4 h = ((const uint4*)hq)[4*lane + t];
        g[t] = h.x + h.y + h.z + h.w;
    }
    unsigned int gs = g[0]+g[1]+g[2]+g[3], cum = gs;
    #pragma unroll
    for (int off = 1; off < 64; off <<= 1){
        unsigned int v = __shfl_up(cum, off);
        if (lane >= off) cum += v;
    }
    unsigned long long bal = __ballot(cum >= Kthr);
    int L = __ffsll(bal) - 1;
    unsigned int run = __shfl(cum, L) - __shfl(gs, L);
    unsigned int h0 = __shfl(g[0], L), h1 = __shfl(g[1], L), h2 = __shfl(g[2], L);
    if      (run + h0 >= Kthr)           { *Bsel = 4*L;     *below = run; }
    else if (run + h0 + h1 >= Kthr)      { *Bsel = 4*L + 1; *below = run + h0; }
    else if (run + h0 + h1 + h2 >= Kthr) { *Bsel = 4*L + 2; *below = run + h0 + h1; }
    else                                 { *Bsel = 4*L + 3; *below = run + h0 + h1 + h2; }
}

// ---- prep0: xs4g[b*N+n] = (x,y,z,|p|^2); zero stats ----
__global__ __launch_bounds__(256) void k_prep0(const float* __restrict__ xyz, float4* __restrict__ xs4g,
                                               float* __restrict__ st){
    int i = blockIdx.x*256 + threadIdx.x;      // 32 blocks x 256 = 8192
    float x = xyz[3*i], y = xyz[3*i+1], z = xyz[3*i+2];
    xs4g[i] = make_float4(x, y, z, dot3f(x,y,z,x,y,z));
    if (blockIdx.x == 0){
        for (int j = threadIdx.x; j < 640; j += 256) st[j] = 0.f;
    }
}

// ---------------- KNN: 2 queries/block, 2 waves/query, two-level radix, fused h1 stats ----------------
__global__ __launch_bounds__(256) void k_knn(const float4* __restrict__ xs4g,
                                             const float* __restrict__ W1, const float* __restrict__ b1,
                                             int* __restrict__ idx_out,
                                             float* __restrict__ s1sh, float* __restrict__ q1sh){
    __shared__ unsigned int hist[2][256][4];          // 8 KB, 4 replicas
    __shared__ unsigned long long lst[2][LISTCAP];    // 3 KB
    __shared__ int kidx[2][K_];
    __shared__ unsigned int cnt[2];
    __shared__ float sacc[H_], qacc[H_];

    const int tid  = threadIdx.x;
    const int w    = tid >> 6;            // wave 0..3
    const int lane = tid & 63;
    const int qi   = w >> 1;              // query slot 0/1
    const int lq   = tid & 127;           // lane index within the query's 128 threads
    const int b    = blockIdx.x / (N_/2);
    const int q    = (blockIdx.x % (N_/2)) * 2 + qi;
    const int bN   = b * N_;

    for (int i = tid; i < 2048; i += 256) ((unsigned int*)hist)[i] = 0u;
    if (tid < 2) cnt[tid] = 0u;
    if (tid < H_){ sacc[tid] = 0.f; qacc[tid] = 0.f; }
    __syncthreads();                                   // B1

    const float4 qp = xs4g[bN + q];
    const float qx = qp.x, qy = qp.y, qz = qp.z, sqq = qp.w;

    // pass 1: 16 candidates/lane, cache flipped dists, coarse histogram (sign+7exp)
    unsigned int fv[16];
    #pragma unroll
    for (int j = 0; j < 16; ++j){
        int c = j*128 + lq;
        float4 pt = xs4g[bN + c];
        float d = fmaf(-2.0f, dot3f(qx,qy,qz, pt.x,pt.y,pt.z), sqq) + pt.w;
        unsigned int f = flip_f32(d);
        fv[j] = f;
        atomicAdd(&hist[qi][f >> 24][lane & 3], 1u);
    }
    __syncthreads();                                   // B2

    int B0; unsigned int lt0;
    hsel4(&hist[qi][0][0], lane, (unsigned)K_, &B0, &lt0);
    unsigned int Kp = (unsigned)K_ - lt0;
    __syncthreads();                                   // B3 (all hsel reads done)

    for (int i = tid; i < 2048; i += 256) ((unsigned int*)hist)[i] = 0u;
    __syncthreads();                                   // B4 (reset done)

    #pragma unroll
    for (int j = 0; j < 16; ++j){
        if ((int)(fv[j] >> 24) == B0)
            atomicAdd(&hist[qi][(fv[j] >> 16) & 0xFF][lane & 3], 1u);
    }
    __syncthreads();                                   // B5

    int B1s; unsigned int lt1;
    hsel4(&hist[qi][0][0], lane, Kp, &B1s, &lt1);

    // compaction: cross-wave positions via per-query counter reservation
    const unsigned long long mlt = (lane == 63) ? ~0ull >> 1 : (1ull << lane) - 1ull;
    #pragma unroll
    for (int j = 0; j < 16; ++j){
        unsigned int f = fv[j];
        int top = (int)(f >> 24);
        bool surv = (top < B0) || (top == B0 && (int)((f >> 16) & 0xFF) <= B1s);
        unsigned long long sb = __ballot(surv);
        if (sb){
            unsigned int t = (unsigned int)__popcll(sb);
            unsigned int base;
            if (lane == 0) base = atomicAdd(&cnt[qi], t);
            base = __shfl(base, 0, 64);
            unsigned int pos = base + (unsigned int)__popcll(sb & mlt);
            if (surv && pos < (unsigned)LISTCAP)
                lst[qi][pos] = ((unsigned long long)f << 32) | (unsigned int)(j*128 + lq);
        }
    }
    __syncthreads();                                   // B6

    int m = (int)cnt[qi]; if (m > LISTCAP) m = LISTCAP;

    // rank-select (keys unique: idx in low bits) -> exact top_k order
    int* outp = idx_out + ((size_t)bN + q) * K_;
    for (int i = lq; i < m; i += 128){
        unsigned long long my = lst[qi][i];
        int rank = 0;
        for (int jj = 0; jj < m; ++jj)
            rank += (lst[qi][jj] < my) ? 1 : 0;
        if (rank < K_){
            int id = (int)(unsigned int)(my & 0xFFFFFFFFull);
            outp[rank] = id;
            kidx[qi][rank] = id;
        }
    }
    __syncthreads();                                   // B7

    // fused h1 stats: ch = lq&31 handles 8 rows (rowgroup lq>>5)
    {
        const int ch = lq & 31, rg = lq >> 5;
        float w1a = W1[ch], w1b = W1[H_+ch], w1c = W1[2*H_+ch], b1c = b1[ch];
        float s = 0.f, qq = 0.f;
        #pragma unroll
        for (int r = 0; r < 8; ++r){
            int id = kidx[qi][rg*8 + r];
            float4 pn = xs4g[bN + id];
            float rx = pn.x - qx, ry = pn.y - qy, rz = pn.z - qz;
            float h = fmaxf(fmaf(rx, w1a, fmaf(ry, w1b, fmaf(rz, w1c, b1c))), 0.0f);
            s += h; qq = fmaf(h, h, qq);
        }
        s  += __shfl_xor(s, 32, 64);
        qq += __shfl_xor(qq, 32, 64);
        if (lane < 32){ atomicAdd(&sacc[lane], s); atomicAdd(&qacc[lane], qq); }
    }
    __syncthreads();                                   // B8
    if (tid < H_){
        int sh = (blockIdx.x & 7) * 32 + tid;
        atomicAdd(&s1sh[sh], sacc[tid]);
        atomicAdd(&q1sh[sh], qacc[tid]);
    }
}

// ---------------- h1 (raw) ----------------
__device__ __forceinline__ void compute_h1(const float* __restrict__ xyz, const int* __restrict__ idx, int r,
                                           const float* __restrict__ W1, const float* __restrict__ b1, float* h1){
    int b = r >> 16;
    int n = (r >> 5) & (N_-1);
    int id = idx[r];
    const float* pc = xyz + ((size_t)b*N_ + n)*3;
    const float* pn = xyz + ((size_t)b*N_ + id)*3;
    float rx = pn[0]-pc[0], ry = pn[1]-pc[1], rz = pn[2]-pc[2];
    #pragma unroll
    for (int j = 0; j < H_; ++j){
        float a = fmaf(rx, W1[j], fmaf(ry, W1[H_+j], fmaf(rz, W1[2*H_+j], b1[j])));
        h1[j] = fmaxf(a, 0.0f);
    }
}

// ---- prep2: points->f16 pairs; W2' = a1(.)W2 f16 B-frags; b2' = b2 + bb1@W2 (shadow-summed s1/q1) ----
__global__ __launch_bounds__(256) void k_prep2(const float* __restrict__ points,
                                               const float* __restrict__ s1s, const float* __restrict__ q1s,
                                               const float* __restrict__ g1, const float* __restrict__ be1,
                                               const float* __restrict__ W2, const float* __restrict__ b2,
                                               unsigned int* __restrict__ pf16, unsigned int* __restrict__ W2f,
                                               float* __restrict__ b2p){
    int flat = blockIdx.x*256 + threadIdx.x;
    if (flat < 65536){
        pf16[flat] = pk2(points[2*flat], points[2*flat+1]);
    } else if (flat < 66048){
        int d = flat - 65536;              // W2f dword index = (step*64+lane)*4+jj
        int jj = d & 3, lane = (d >> 2) & 63, step = d >> 8;
        int col = lane & 31;
        int k0 = step*16 + (lane >> 5)*8 + 2*jj;
        float m0 = sh8(s1s,k0)*INVR_,   v0 = sh8(q1s,k0)*INVR_   - m0*m0;
        float m1 = sh8(s1s,k0+1)*INVR_, v1 = sh8(q1s,k0+1)*INVR_ - m1*m1;
        float a0  = g1[k0]   / sqrtf(v0 + EPS_);
        float a1v = g1[k0+1] / sqrtf(v1 + EPS_);
        W2f[d] = pk2(a0*W2[k0*H_ + col], a1v*W2[(k0+1)*H_ + col]);
    } else if (flat < 66080){
        int col = flat - 66048;
        float acc = b2[col];
        #pragma unroll 4
        for (int h = 0; h < H_; ++h){
            float mm = sh8(s1s,h)*INVR_, vv = sh8(q1s,h)*INVR_ - mm*mm;
            float aa = g1[h] / sqrtf(vv + EPS_);
            float bb = fmaf(-aa, mm, be1[h]);
            acc = fmaf(bb, W2[h*H_ + col], acc);
        }
        b2p[col] = acc;
    }
}

// ---- k_h2: h1 scalar -> layer2 via MFMA 32x32x16 f16 (bias via C-init) -> raw h2 f16 + stats ----
__global__ __launch_bounds__(256,3) void k_h2(const float* __restrict__ xyz, const int* __restrict__ idx,
                                              const float* __restrict__ W1, const float* __restrict__ b1,
                                              const uint4* __restrict__ W2f, const float* __restrict__ b2p,
                                              unsigned short* __restrict__ h2g,
                                              float* gsum, float* gsq){
    __shared__ float redS[H_], redQ[H_];
    const int tid = threadIdx.x, lane = tid & 63, w = tid >> 6;
    const int half = lane >> 5, m = lane & 31;
    if (tid < H_){ redS[tid] = 0.f; redQ[tid] = 0.f; }
    __syncthreads();

    int r = blockIdx.x*256 + tid;
    float h1[H_];
    compute_h1(xyz, idx, r, W1, b1, h1);
    unsigned int h1p[16];
    #pragma unroll
    for (int i = 0; i < 16; ++i) h1p[i] = pk2(h1[2*i], h1[2*i+1]);

    union { uint4 u4; f16x8 v; } Bf0, Bf1;
    Bf0.u4 = W2f[lane];
    Bf1.u4 = W2f[64 + lane];
    float b2c = b2p[m];

    const int rB = blockIdx.x*256 + w*64;
    float s = 0.f, q = 0.f;
    #pragma unroll
    for (int t = 0; t < 2; ++t){
        const int src = t*32 + m;
        union { unsigned int u[4]; f16x8 v; } a0, a1f;
        #pragma unroll
        for (int jj = 0; jj < 4; ++jj){
            unsigned int lo = __shfl(h1p[jj],     src, 64);
            unsigned int hi = __shfl(h1p[4 + jj], src, 64);
            a0.u[jj] = half ? hi : lo;
        }
        #pragma unroll
        for (int jj = 0; jj < 4; ++jj){
            unsigned int lo = __shfl(h1p[8 + jj],  src, 64);
            unsigned int hi = __shfl(h1p[12 + jj], src, 64);
            a1f.u[jj] = half ? hi : lo;
        }
        f32x16 acc;
        #pragma unroll
        for (int i = 0; i < 16; ++i) acc[i] = b2c;
        acc = __builtin_amdgcn_mfma_f32_32x32x16_f16(a0.v,  Bf0.v, acc, 0, 0, 0);
        acc = __builtin_amdgcn_mfma_f32_32x32x16_f16(a1f.v, Bf1.v, acc, 0, 0, 0);
        #pragma unroll
        for (int i = 0; i < 16; ++i){
            float v = fmaxf(acc[i], 0.0f);
            int row = rB + t*32 + (i & 3) + 8*(i >> 2) + 4*half;
            union { _Float16 h; unsigned short u; } cv; cv.h = (_Float16)v;
            h2g[(size_t)row*H_ + m] = cv.u;
            s += v; q = fmaf(v, v, q);
        }
    }
    s += __shfl_xor(s, 32, 64);
    q += __shfl_xor(q, 32, 64);
    if (lane < 32){ atomicAdd(&redS[m], s); atomicAdd(&redQ[m], q); }
    __syncthreads();
    if (tid < H_){ atomicAdd(&gsum[tid], redS[tid]); atomicAdd(&gsq[tid], redQ[tid]); }
}

// ---- prep3: W3'' = aa2(.)W3 (+ b3' bias row at step 32) -> f16 B-frags for K=528 ----
__global__ __launch_bounds__(256) void k_prep3(const float* __restrict__ W3, const float* __restrict__ b3,
                                               const float* __restrict__ s2, const float* __restrict__ q2,
                                               const float* __restrict__ g2, const float* __restrict__ be2,
                                               unsigned int* __restrict__ W3f){
    int d = blockIdx.x*256 + threadIdx.x;     // 33*256 = 8448 dwords
    int jj = d & 3, lane = (d >> 2) & 63, step = d >> 8;
    int col = lane & 31;
    int off = (lane >> 5)*8 + 2*jj;
    float v0, v1;
    if (step < 32){
        int h = step, c0 = off;
        float mm = s2[h]*INVR_, vv = q2[h]*INVR_ - mm*mm;
        float aa = g2[h] / sqrtf(vv + EPS_);
        v0 = aa * W3[h*512 + c0*COUT_ + col];
        v1 = aa * W3[h*512 + (c0+1)*COUT_ + col];
    } else {
        int c0 = off;
        v0 = b3[c0*COUT_ + col]; v1 = b3[(c0+1)*COUT_ + col];
        #pragma unroll 4
        for (int h = 0; h < H_; ++h){
            float mm = s2[h]*INVR_, vv = q2[h]*INVR_ - mm*mm;
            float aa = g2[h] / sqrtf(vv + EPS_);
            float bb = fmaf(-aa, mm, be2[h]);
            v0 = fmaf(bb, W3[h*512 + c0*COUT_ + col], v0);
            v1 = fmaf(bb, W3[h*512 + (c0+1)*COUT_ + col], v1);
        }
    }
    W3f[d] = pk2(v0, v1);
}

// ---- k_out: A = outer(h2,gp) built f16-packed from memory; 33-step MFMA 32x32x16; max over k ----
__global__ __launch_bounds__(256,3) void k_out(const int* __restrict__ idx,
                                               const unsigned int* __restrict__ pf16,
                                               const unsigned int* __restrict__ h2u,
                                               const uint4* __restrict__ W3f,
                                               float* __restrict__ out_pre, float* gsum, float* gsq){
    __shared__ float redS[COUT_], redQ[COUT_];
    const int tid = threadIdx.x, lane = tid & 63, w = tid >> 6;
    const int half = lane >> 5, m = lane & 31;
    if (tid < COUT_){ redS[tid] = 0.f; redQ[tid] = 0.f; }
    __syncthreads();

    const int rB = blockIdx.x*256 + w*64;
    const uint4* Wf = W3f + lane;

    #pragma unroll
    for (int t = 0; t < 2; ++t){
        int row = rB + t*32 + m;
        int b = row >> 16;
        int id = idx[row];
        const uint4* gpp = (const uint4*)(pf16 + ((size_t)b*N_ + id)*8);
        uint4 ga = gpp[0], gb = gpp[1];
        unsigned int gsel[4];
        gsel[0] = half ? gb.x : ga.x;
        gsel[1] = half ? gb.y : ga.y;
        gsel[2] = half ? gb.z : ga.z;
        gsel[3] = half ? gb.w : ga.w;
        const uint4* hp = (const uint4*)(h2u + (size_t)row*16);
        uint4 hA = hp[0], hB = hp[1], hC = hp[2], hD = hp[3];
        unsigned int h2p[16] = {hA.x,hA.y,hA.z,hA.w, hB.x,hB.y,hB.z,hB.w,
                                hC.x,hC.y,hC.z,hC.w, hD.x,hD.y,hD.z,hD.w};
        f32x16 acc;
        #pragma unroll
        for (int i = 0; i < 16; ++i) acc[i] = 0.f;

        #pragma unroll
        for (int kb = 0; kb < 32; ++kb){
            unsigned int hr = h2p[kb >> 1];
            unsigned int hd = __builtin_amdgcn_perm(hr, hr, (kb & 1) ? 0x03020302u : 0x01000100u);
            union { unsigned int u[4]; f16x8 v; } af;
            #pragma unroll
            for (int jj = 0; jj < 4; ++jj) af.u[jj] = pkmul(hd, gsel[jj]);
            union { uint4 u4; f16x8 v; } bf; bf.u4 = Wf[kb*64];
            acc = __builtin_amdgcn_mfma_f32_32x32x16_f16(af.v, bf.v, acc, 0, 0, 0);
        }
        {   // bias step: A = gp, B = b3'
            union { unsigned int u[4]; f16x8 v; } af;
            #pragma unroll
            for (int jj = 0; jj < 4; ++jj) af.u[jj] = gsel[jj];
            union { uint4 u4; f16x8 v; } bf; bf.u4 = Wf[32*64];
            acc = __builtin_amdgcn_mfma_f32_32x32x16_f16(af.v, bf.v, acc, 0, 0, 0);
        }

        float v = acc[0];
        #pragma unroll
        for (int i = 1; i < 16; ++i) v = fmaxf(v, acc[i]);
        v = fmaxf(v, __shfl_xor(v, 32, 64));
        if (lane < 32){
            int g = blockIdx.x*8 + w*2 + t;
            out_pre[(size_t)g*COUT_ + m] = v;
            atomicAdd(&redS[m], v);
            atomicAdd(&redQ[m], v*v);
        }
    }
    __syncthreads();
    if (tid < COUT_){ atomicAdd(&gsum[tid], redS[tid]); atomicAdd(&gsq[tid], redQ[tid]); }
}

__global__ __launch_bounds__(256) void k_bn(const float* __restrict__ out_pre,
                                            const float* __restrict__ s3, const float* __restrict__ q3,
                                            const float* __restrict__ gbn, const float* __restrict__ bbn,
                                            float* __restrict__ out){
    int i = blockIdx.x*256 + threadIdx.x;
    int o = i & (COUT_-1);
    float mm = s3[o] * INVBN_;
    float vv = q3[o] * INVBN_ - mm*mm;
    float aa = gbn[o] / sqrtf(vv + EPS_);
    out[i] = fmaf(aa, out_pre[i], fmaf(-aa, mm, bbn[o]));
}

extern "C" void kernel_launch(void* const* d_in, const int* in_sizes, int n_in,
                              void* d_out, int out_size, void* d_ws, size_t ws_size,
                              hipStream_t stream){
    const float* xyz    = (const float*)d_in[0];
    const float* points = (const float*)d_in[1];
    const float* W1  = (const float*)d_in[2];
    const float* b1  = (const float*)d_in[3];
    const float* g1  = (const float*)d_in[4];
    const float* be1 = (const float*)d_in[5];
    const float* W2  = (const float*)d_in[6];
    const float* b2  = (const float*)d_in[7];
    const float* g2  = (const float*)d_in[8];
    const float* be2 = (const float*)d_in[9];
    const float* W3  = (const float*)d_in[10];
    const float* b3  = (const float*)d_in[11];
    const float* gbn = (const float*)d_in[12];
    const float* bbn = (const float*)d_in[13];
    float* out = (float*)d_out;

    // ws layout (bytes):
    char* base = (char*)d_ws;
    int*            idx     = (int*)(base + 0);                     // 1,048,576
    float*          out_pre = (float*)(base + 1048576);             // 1,048,576
    unsigned short* h2g     = (unsigned short*)(base + 2097152);    // 16,777,216
    unsigned int*   pf16    = (unsigned int*)(base + 18874368);     //    262,144
    unsigned int*   W3f     = (unsigned int*)(base + 19136512);     //     33,792
    unsigned int*   W2f     = (unsigned int*)(base + 19170304);     //      2,048
    float*          b2p     = (float*)(base + 19172352);            //        128
    float*          st      = (float*)(base + 19172480);            //      2,560
    float4*         xs4g    = (float4*)(base + 19175040);           //    131,072
    // st floats: s1s[256] | q1s[256] | s2[32] | q2[32] | s3[32] | q3[32]
    float *s1s=st, *q1s=st+256, *s2=st+512, *q2=st+544, *s3=st+576, *q3=st+608;

    hipLaunchKernelGGL(k_prep0,  dim3(32),          dim3(256), 0, stream, xyz, xs4g, st);
    hipLaunchKernelGGL(k_knn,    dim3(B_*N_/2),     dim3(256), 0, stream, xs4g, W1, b1, idx, s1s, q1s);
    hipLaunchKernelGGL(k_prep2,  dim3(260),         dim3(256), 0, stream, points, s1s, q1s, g1, be1, W2, b2,
                       pf16, W2f, b2p);
    hipLaunchKernelGGL(k_h2,     dim3(R_/256),      dim3(256), 0, stream, xyz, idx, W1, b1,
                       (const uint4*)W2f, b2p, h2g, s2, q2);
    hipLaunchKernelGGL(k_prep3,  dim3(33),          dim3(256), 0, stream, W3, b3, s2, q2, g2, be2, W3f);
    hipLaunchKernelGGL(k_out,    dim3(R_/256),      dim3(256), 0, stream, idx, pf16, (const unsigned int*)h2g,
                       (const uint4*)W3f, out_pre, s3, q3);
    hipLaunchKernelGGL(k_bn,     dim3(B_*N_*COUT_/256), dim3(256), 0, stream, out_pre, s3, q3, gbn, bbn, out);
}

// Round 8
// 180.419 us; speedup vs baseline: 2.6510x; 1.0357x over previous
//
#include <hip/hip_runtime.h>

#define B_ 4
#define N_ 2048
#define K_ 32
#define CIN_ 16
#define COUT_ 32
#define H_ 32
#define R_ (B_*N_*K_)      // 262144 rows through the weight-net
#define EPS_ 1e-5f
#define INVR_ (1.0f/(float)R_)
#define INVBN_ (1.0f/(float)(B_*N_))
#define LISTCAP 192
#define NSH 16             // stat shadows

typedef __attribute__((ext_vector_type(8)))  _Float16 f16x8;
typedef __attribute__((ext_vector_type(2)))  __fp16   hw16x2;   // builtin cvt_pkrtz return type
typedef __attribute__((ext_vector_type(2)))  _Float16 f16x2;
typedef __attribute__((ext_vector_type(16))) float    f32x16;

__device__ __forceinline__ float dot3f(float ax,float ay,float az,float bx,float by,float bz){
    return fmaf(az,bz, fmaf(ay,by, ax*bx));
}
__device__ __forceinline__ unsigned int flip_f32(float d){
    unsigned int u = __float_as_uint(d);
    return u ^ ((unsigned int)(((int)u) >> 31) | 0x80000000u);
}
__device__ __forceinline__ unsigned int pk2(float a, float b){   // packed f16 pair (RTZ)
    union { hw16x2 v; unsigned int u; } c;
    c.v = __builtin_amdgcn_cvt_pkrtz(a, b);
    return c.u;
}
__device__ __forceinline__ unsigned int pkmul(unsigned int a, unsigned int b){  // v_pk_mul_f16
    union { unsigned int u; f16x2 v; } x, y, r;
    x.u = a; y.u = b; r.v = x.v * y.v; return r.u;
}
// sum of NSH shadow accumulators
__device__ __forceinline__ float shsum(const float* __restrict__ p, int k){
    float s = 0.f;
    #pragma unroll
    for (int i = 0; i < NSH; ++i) s += p[i*32 + k];
    return s;
}

// wave hist select over 4-replica histogram: smallest bucket with cumulative >= Kthr
__device__ __forceinline__ void hsel4(const unsigned int* hq /*256 buckets x uint4*/, int lane,
                                      unsigned int Kthr, int* Bsel, unsigned int* below){
    unsigned int g[4];
    #pragma unroll
    for (int t = 0; t < 4; ++t){
        uint4 h = ((const uint4*)hq)[4*lane + t];
        g[t] = h.x + h.y + h.z + h.w;
    }
    unsigned int gs = g[0]+g[1]+g[2]+g[3], cum = gs;
    #pragma unroll
    for (int off = 1; off < 64; off <<= 1){
        unsigned int v = __shfl_up(cum, off);
        if (lane >= off) cum += v;
    }
    unsigned long long bal = __ballot(cum >= Kthr);
    int L = __ffsll(bal) - 1;
    unsigned int run = __shfl(cum, L) - __shfl(gs, L);
    unsigned int h0 = __shfl(g[0], L), h1 = __shfl(g[1], L), h2 = __shfl(g[2], L);
    if      (run + h0 >= Kthr)           { *Bsel = 4*L;     *below = run; }
    else if (run + h0 + h1 >= Kthr)      { *Bsel = 4*L + 1; *below = run + h0; }
    else if (run + h0 + h1 + h2 >= Kthr) { *Bsel = 4*L + 2; *below = run + h0 + h1; }
    else                                 { *Bsel = 4*L + 3; *below = run + h0 + h1 + h2; }
}

// ---- prep0: xs4g[b*N+n] = (x,y,z,|p|^2); zero stats ----
__global__ __launch_bounds__(256) void k_prep0(const float* __restrict__ xyz, float4* __restrict__ xs4g,
                                               float* __restrict__ st){
    int i = blockIdx.x*256 + threadIdx.x;      // 32 blocks x 256 = 8192
    float x = xyz[3*i], y = xyz[3*i+1], z = xyz[3*i+2];
    xs4g[i] = make_float4(x, y, z, dot3f(x,y,z,x,y,z));
    if (blockIdx.x == 0){
        for (int j = threadIdx.x; j < 1152; j += 256) st[j] = 0.f;
    }
}

// ---------------- KNN: 1 wave/query, fully wave-autonomous (ZERO barriers), fused h1 stats ----------------
__global__ __launch_bounds__(256,4) void k_knn(const float4* __restrict__ xs4g,
                                               const float* __restrict__ W1, const float* __restrict__ b1,
                                               int* __restrict__ idx_out,
                                               float* __restrict__ s1sh, float* __restrict__ q1sh){
    __shared__ uint4 hist4[4][256];                   // 16 KB: per-wave 256 buckets x4 replicas
    __shared__ unsigned long long lst[4][LISTCAP];    // 6 KB
    __shared__ int kidx[4][K_];                       // 0.5 KB

    const int tid  = threadIdx.x;
    const int w    = tid >> 6;
    const int lane = tid & 63;
    const int half = lane >> 5;
    const int b    = blockIdx.x >> 9;                 // 512 query-groups per batch
    const int q    = ((blockIdx.x & 511) << 2) + w;
    const int bN   = b * N_;
    unsigned int* hw = (unsigned int*)hist4[w];

    const uint4 z4 = make_uint4(0,0,0,0);
    hist4[w][lane] = z4; hist4[w][64+lane] = z4; hist4[w][128+lane] = z4; hist4[w][192+lane] = z4;

    const float4 qp = xs4g[bN + q];
    const float qx = qp.x, qy = qp.y, qz = qp.z, sqq = qp.w;

    // pass 1: 32 candidates/lane, cache flipped dists, coarse histogram (sign+7exp)
    unsigned int fv[32];
    #pragma unroll
    for (int j = 0; j < 32; ++j){
        int c = j*64 + lane;
        float4 pt = xs4g[bN + c];
        float d = fmaf(-2.0f, dot3f(qx,qy,qz, pt.x,pt.y,pt.z), sqq) + pt.w;
        unsigned int f = flip_f32(d);
        fv[j] = f;
        atomicAdd(&hw[(f >> 24)*4 + (lane & 3)], 1u);
    }
    int B0; unsigned int lt0;
    hsel4(hw, lane, (unsigned)K_, &B0, &lt0);
    unsigned int Kp = (unsigned)K_ - lt0;

    // refine bucket B0 on bits 23:16
    hist4[w][lane] = z4; hist4[w][64+lane] = z4; hist4[w][128+lane] = z4; hist4[w][192+lane] = z4;
    #pragma unroll
    for (int j = 0; j < 32; ++j){
        if ((int)(fv[j] >> 24) == B0)
            atomicAdd(&hw[((fv[j] >> 16) & 0xFF)*4 + (lane & 3)], 1u);
    }
    int B1s; unsigned int lt1;
    hsel4(hw, lane, Kp, &B1s, &lt1);

    // ballot-compaction (wave-synchronous running count, no LDS counter)
    const unsigned long long mlt = (lane == 63) ? ~0ull >> 1 : (1ull << lane) - 1ull;
    unsigned int cnt = 0;
    #pragma unroll
    for (int j = 0; j < 32; ++j){
        unsigned int f = fv[j];
        int top = (int)(f >> 24);
        bool surv = (top < B0) || (top == B0 && (int)((f >> 16) & 0xFF) <= B1s);
        unsigned long long sb = __ballot(surv);
        unsigned int pos = cnt + (unsigned int)__popcll(sb & mlt);
        if (surv && pos < (unsigned)LISTCAP)
            lst[w][pos] = ((unsigned long long)f << 32) | (unsigned int)(j*64 + lane);
        cnt += (unsigned int)__popcll(sb);
    }
    int m = (int)cnt; if (m > LISTCAP) m = LISTCAP;

    // rank-select (keys unique: idx in low bits) -> exact top_k tie-break
    int* outp = idx_out + ((size_t)bN + q) * K_;
    for (int i = lane; i < m; i += 64){
        unsigned long long my = lst[w][i];
        int rank = 0;
        for (int jj = 0; jj < m; ++jj)
            rank += (lst[w][jj] < my) ? 1 : 0;
        if (rank < K_){
            int id = (int)(unsigned int)(my & 0xFFFFFFFFull);
            outp[rank] = id;
            kidx[w][rank] = id;
        }
    }

    // fused h1 stats: ch = lane&31; halves split the 32 neighbors (16 each)
    {
        const int ch = lane & 31;
        float w1a = W1[ch], w1b = W1[H_+ch], w1c = W1[2*H_+ch], b1c = b1[ch];
        float s = 0.f, qq = 0.f;
        #pragma unroll
        for (int r = 0; r < 16; ++r){
            int idr = kidx[w][half*16 + r];            // wave-uniform LDS broadcast
            float4 pn = xs4g[bN + idr];
            float rx = pn.x - qx, ry = pn.y - qy, rz = pn.z - qz;
            float h = fmaxf(fmaf(rx, w1a, fmaf(ry, w1b, fmaf(rz, w1c, b1c))), 0.0f);
            s += h; qq = fmaf(h, h, qq);
        }
        s  += __shfl_xor(s, 32, 64);
        qq += __shfl_xor(qq, 32, 64);
        if (lane < 32){
            int sh = (blockIdx.x & (NSH-1)) * 32 + ch;
            atomicAdd(&s1sh[sh], s);
            atomicAdd(&q1sh[sh], qq);
        }
    }
}

// ---------------- h1 (raw) from xs4g ----------------
__device__ __forceinline__ void compute_h1v(const float4* __restrict__ xs4g, const int* __restrict__ idx, int r,
                                            const float* __restrict__ W1, const float* __restrict__ b1, float* h1){
    int b = r >> 16;
    int n = (r >> 5) & (N_-1);
    int id = idx[r];
    float4 pc = xs4g[b*N_ + n];
    float4 pn = xs4g[b*N_ + id];
    float rx = pn.x - pc.x, ry = pn.y - pc.y, rz = pn.z - pc.z;
    #pragma unroll
    for (int j = 0; j < H_; ++j){
        float a = fmaf(rx, W1[j], fmaf(ry, W1[H_+j], fmaf(rz, W1[2*H_+j], b1[j])));
        h1[j] = fmaxf(a, 0.0f);
    }
}

// ---- prep2: points->f16 pairs; W2' = a1(.)W2 f16 frags; b2' = b2 + bb1@W2 (shadow-summed s1/q1) ----
__global__ __launch_bounds__(256) void k_prep2(const float* __restrict__ points,
                                               const float* __restrict__ s1s, const float* __restrict__ q1s,
                                               const float* __restrict__ g1, const float* __restrict__ be1,
                                               const float* __restrict__ W2, const float* __restrict__ b2,
                                               unsigned int* __restrict__ pf16, unsigned int* __restrict__ W2f,
                                               float* __restrict__ b2p){
    int flat = blockIdx.x*256 + threadIdx.x;
    if (flat < 65536){
        pf16[flat] = pk2(points[2*flat], points[2*flat+1]);
    } else if (flat < 66048){
        int d = flat - 65536;              // W2f dword index = (s*64+lane)*4+jj
        int jj = d & 3, lane = (d >> 2) & 63, s = d >> 8;
        int col = lane & 31;
        int k0 = s*16 + (lane >> 5)*8 + 2*jj;
        float m0 = shsum(s1s,k0)*INVR_,   v0 = shsum(q1s,k0)*INVR_   - m0*m0;
        float m1 = shsum(s1s,k0+1)*INVR_, v1 = shsum(q1s,k0+1)*INVR_ - m1*m1;
        float a0  = g1[k0]   / sqrtf(v0 + EPS_);
        float a1v = g1[k0+1] / sqrtf(v1 + EPS_);
        W2f[d] = pk2(a0*W2[k0*H_ + col], a1v*W2[(k0+1)*H_ + col]);
    } else if (flat < 66080){
        int col = flat - 66048;
        float acc = b2[col];
        #pragma unroll 4
        for (int h = 0; h < H_; ++h){
            float mm = shsum(s1s,h)*INVR_, vv = shsum(q1s,h)*INVR_ - mm*mm;
            float aa = g1[h] / sqrtf(vv + EPS_);
            float bb = fmaf(-aa, mm, be1[h]);
            acc = fmaf(bb, W2[h*H_ + col], acc);
        }
        b2p[col] = acc;
    }
}

// ---- k_h2stats: h1 -> layer2 MFMA (C[row][ch]) -> relu -> per-channel stats ONLY (no h2 store) ----
__global__ __launch_bounds__(256,3) void k_h2stats(const float4* __restrict__ xs4g, const int* __restrict__ idx,
                                                   const float* __restrict__ W1, const float* __restrict__ b1,
                                                   const uint4* __restrict__ W2f, const float* __restrict__ b2p,
                                                   float* gsum, float* gsq){
    __shared__ float redS[H_], redQ[H_];
    const int tid = threadIdx.x, lane = tid & 63, w = tid >> 6;
    const int half = lane >> 5, m = lane & 31;
    if (tid < H_){ redS[tid] = 0.f; redQ[tid] = 0.f; }
    __syncthreads();

    int r = blockIdx.x*256 + tid;
    float h1[H_];
    compute_h1v(xs4g, idx, r, W1, b1, h1);
    unsigned int h1p[16];
    #pragma unroll
    for (int i = 0; i < 16; ++i) h1p[i] = pk2(h1[2*i], h1[2*i+1]);

    union { uint4 u4; f16x8 v; } Bf0, Bf1;
    Bf0.u4 = W2f[lane];
    Bf1.u4 = W2f[64 + lane];
    float b2c = b2p[m];

    float s = 0.f, q = 0.f;
    #pragma unroll
    for (int t = 0; t < 2; ++t){
        const int src = t*32 + m;
        union { unsigned int u[4]; f16x8 v; } a0, a1f;
        #pragma unroll
        for (int jj = 0; jj < 4; ++jj){
            unsigned int lo = __shfl(h1p[jj],     src, 64);
            unsigned int hi = __shfl(h1p[4 + jj], src, 64);
            a0.u[jj] = half ? hi : lo;
        }
        #pragma unroll
        for (int jj = 0; jj < 4; ++jj){
            unsigned int lo = __shfl(h1p[8 + jj],  src, 64);
            unsigned int hi = __shfl(h1p[12 + jj], src, 64);
            a1f.u[jj] = half ? hi : lo;
        }
        f32x16 acc;
        #pragma unroll
        for (int i = 0; i < 16; ++i) acc[i] = b2c;
        acc = __builtin_amdgcn_mfma_f32_32x32x16_f16(a0.v,  Bf0.v, acc, 0, 0, 0);
        acc = __builtin_amdgcn_mfma_f32_32x32x16_f16(a1f.v, Bf1.v, acc, 0, 0, 0);
        #pragma unroll
        for (int i = 0; i < 16; ++i){
            float v = fmaxf(acc[i], 0.0f);
            s += v; q = fmaf(v, v, q);
        }
    }
    s += __shfl_xor(s, 32, 64);
    q += __shfl_xor(q, 32, 64);
    if (lane < 32){ atomicAdd(&redS[m], s); atomicAdd(&redQ[m], q); }
    __syncthreads();
    if (tid < H_){ atomicAdd(&gsum[tid], redS[tid]); atomicAdd(&gsq[tid], redQ[tid]); }
}

// ---- prep3: W3'' = aa2(.)W3 (+ b3' bias row at step 32) -> f16 B-frags for K=528 ----
__global__ __launch_bounds__(256) void k_prep3(const float* __restrict__ W3, const float* __restrict__ b3,
                                               const float* __restrict__ s2, const float* __restrict__ q2,
                                               const float* __restrict__ g2, const float* __restrict__ be2,
                                               unsigned int* __restrict__ W3f){
    int d = blockIdx.x*256 + threadIdx.x;     // 33*256 = 8448 dwords
    int jj = d & 3, lane = (d >> 2) & 63, step = d >> 8;
    int col = lane & 31;
    int off = (lane >> 5)*8 + 2*jj;
    float v0, v1;
    if (step < 32){
        int h = step, c0 = off;
        float mm = s2[h]*INVR_, vv = q2[h]*INVR_ - mm*mm;
        float aa = g2[h] / sqrtf(vv + EPS_);
        v0 = aa * W3[h*512 + c0*COUT_ + col];
        v1 = aa * W3[h*512 + (c0+1)*COUT_ + col];
    } else {
        int c0 = off;
        v0 = b3[c0*COUT_ + col]; v1 = b3[(c0+1)*COUT_ + col];
        #pragma unroll 4
        for (int h = 0; h < H_; ++h){
            float mm = s2[h]*INVR_, vv = q2[h]*INVR_ - mm*mm;
            float aa = g2[h] / sqrtf(vv + EPS_);
            float bb = fmaf(-aa, mm, be2[h]);
            v0 = fmaf(bb, W3[h*512 + c0*COUT_ + col], v0);
            v1 = fmaf(bb, W3[h*512 + (c0+1)*COUT_ + col], v1);
        }
    }
    W3f[d] = pk2(v0, v1);
}

// ---- k_out (FUSED): h1 -> layer2 MFMA swapped (C[ch][row]) -> h2 in regs -> layer3 MFMA -> max ----
// Layer-2 operand swap: A = W2'^T frags (== W2f bits), B = h1 frags (== old A-frag construction).
// Lane (half,m) then holds h2 channels of data-row t*32+m across its C-regs + partner (xor 32).
__global__ __launch_bounds__(256,3) void k_out(const float4* __restrict__ xs4g, const int* __restrict__ idx,
                                               const float* __restrict__ W1, const float* __restrict__ b1,
                                               const uint4* __restrict__ W2f, const float* __restrict__ b2p,
                                               const unsigned int* __restrict__ pf16,
                                               const uint4* __restrict__ W3f,
                                               float* __restrict__ out_pre, float* gsum, float* gsq){
    __shared__ float redS[COUT_], redQ[COUT_];
    const int tid = threadIdx.x, lane = tid & 63, w = tid >> 6;
    const int half = lane >> 5, m = lane & 31;
    if (tid < COUT_){ redS[tid] = 0.f; redQ[tid] = 0.f; }
    __syncthreads();

    const int rB = blockIdx.x*256 + w*64;
    int r = blockIdx.x*256 + tid;

    float h1[H_];
    compute_h1v(xs4g, idx, r, W1, b1, h1);
    unsigned int h1p[16];
    #pragma unroll
    for (int i = 0; i < 16; ++i) h1p[i] = pk2(h1[2*i], h1[2*i+1]);

    union { uint4 u4; f16x8 v; } A0, A1;     // W2'^T A-frags (same bits as W2f)
    A0.u4 = W2f[lane];
    A1.u4 = W2f[64 + lane];
    float b2v[16];                            // bias per C-reg: ch = (i&3)+8*(i>>2)+4*half
    #pragma unroll
    for (int i = 0; i < 16; ++i) b2v[i] = b2p[(i&3) + 8*(i>>2) + 4*half];

    const uint4* Wf = W3f + lane;

    #pragma unroll
    for (int t = 0; t < 2; ++t){
        const int src = t*32 + m;
        // B-frags = h1 of data-row t*32+m (same construction as h2stats' A-frags)
        union { unsigned int u[4]; f16x8 v; } B0f, B1f;
        #pragma unroll
        for (int jj = 0; jj < 4; ++jj){
            unsigned int lo = __shfl(h1p[jj],     src, 64);
            unsigned int hi = __shfl(h1p[4 + jj], src, 64);
            B0f.u[jj] = half ? hi : lo;
        }
        #pragma unroll
        for (int jj = 0; jj < 4; ++jj){
            unsigned int lo = __shfl(h1p[8 + jj],  src, 64);
            unsigned int hi = __shfl(h1p[12 + jj], src, 64);
            B1f.u[jj] = half ? hi : lo;
        }
        f32x16 c2;
        #pragma unroll
        for (int i = 0; i < 16; ++i) c2[i] = b2v[i];
        c2 = __builtin_amdgcn_mfma_f32_32x32x16_f16(A0.v, B0f.v, c2, 0, 0, 0);
        c2 = __builtin_amdgcn_mfma_f32_32x32x16_f16(A1.v, B1f.v, c2, 0, 0, 0);

        // relu + pack + half-exchange -> h2p[16] = row (t*32+m)'s 32 channels, f16-packed
        unsigned int h2p[16];
        #pragma unroll
        for (int p = 0; p < 8; ++p){
            float v0 = fmaxf(c2[2*p],   0.0f);
            float v1 = fmaxf(c2[2*p+1], 0.0f);
            unsigned int ow = pk2(v0, v1);
            unsigned int ot = __shfl_xor(ow, 32, 64);
            int a = p >> 1, bb = p & 1;
            h2p[4*a + 2*half     + bb] = ow;
            h2p[4*a + 2*(1-half) + bb] = ot;
        }

        // gp for row t*32+m
        int row = rB + t*32 + m;
        int bb_ = row >> 16;
        int idr = idx[row];
        const uint4* gpp = (const uint4*)(pf16 + ((size_t)bb_*N_ + idr)*8);
        uint4 ga = gpp[0], gb = gpp[1];
        unsigned int gsel[4];
        gsel[0] = half ? gb.x : ga.x;
        gsel[1] = half ? gb.y : ga.y;
        gsel[2] = half ? gb.z : ga.z;
        gsel[3] = half ? gb.w : ga.w;

        f32x16 acc;
        #pragma unroll
        for (int i = 0; i < 16; ++i) acc[i] = 0.f;
        #pragma unroll
        for (int kb = 0; kb < 32; ++kb){
            unsigned int hr = h2p[kb >> 1];
            unsigned int hd = __builtin_amdgcn_perm(hr, hr, (kb & 1) ? 0x03020302u : 0x01000100u);
            union { unsigned int u[4]; f16x8 v; } af;
            #pragma unroll
            for (int jj = 0; jj < 4; ++jj) af.u[jj] = pkmul(hd, gsel[jj]);
            union { uint4 u4; f16x8 v; } bf; bf.u4 = Wf[kb*64];
            acc = __builtin_amdgcn_mfma_f32_32x32x16_f16(af.v, bf.v, acc, 0, 0, 0);
        }
        {   // bias step: A = gp, B = b3'
            union { unsigned int u[4]; f16x8 v; } af;
            #pragma unroll
            for (int jj = 0; jj < 4; ++jj) af.u[jj] = gsel[jj];
            union { uint4 u4; f16x8 v; } bf; bf.u4 = Wf[32*64];
            acc = __builtin_amdgcn_mfma_f32_32x32x16_f16(af.v, bf.v, acc, 0, 0, 0);
        }

        float v = acc[0];
        #pragma unroll
        for (int i = 1; i < 16; ++i) v = fmaxf(v, acc[i]);
        v = fmaxf(v, __shfl_xor(v, 32, 64));
        if (lane < 32){
            int g = blockIdx.x*8 + w*2 + t;
            out_pre[(size_t)g*COUT_ + m] = v;
            atomicAdd(&redS[m], v);
            atomicAdd(&redQ[m], v*v);
        }
    }
    __syncthreads();
    if (tid < COUT_){ atomicAdd(&gsum[tid], redS[tid]); atomicAdd(&gsq[tid], redQ[tid]); }
}

__global__ __launch_bounds__(256) void k_bn(const float* __restrict__ out_pre,
                                            const float* __restrict__ s3, const float* __restrict__ q3,
                                            const float* __restrict__ gbn, const float* __restrict__ bbn,
                                            float* __restrict__ out){
    int i = blockIdx.x*256 + threadIdx.x;
    int o = i & (COUT_-1);
    float mm = s3[o] * INVBN_;
    float vv = q3[o] * INVBN_ - mm*mm;
    float aa = gbn[o] / sqrtf(vv + EPS_);
    out[i] = fmaf(aa, out_pre[i], fmaf(-aa, mm, bbn[o]));
}

extern "C" void kernel_launch(void* const* d_in, const int* in_sizes, int n_in,
                              void* d_out, int out_size, void* d_ws, size_t ws_size,
                              hipStream_t stream){
    const float* xyz    = (const float*)d_in[0];
    const float* points = (const float*)d_in[1];
    const float* W1  = (const float*)d_in[2];
    const float* b1  = (const float*)d_in[3];
    const float* g1  = (const float*)d_in[4];
    const float* be1 = (const float*)d_in[5];
    const float* W2  = (const float*)d_in[6];
    const float* b2  = (const float*)d_in[7];
    const float* g2  = (const float*)d_in[8];
    const float* be2 = (const float*)d_in[9];
    const float* W3  = (const float*)d_in[10];
    const float* b3  = (const float*)d_in[11];
    const float* gbn = (const float*)d_in[12];
    const float* bbn = (const float*)d_in[13];
    float* out = (float*)d_out;

    // ws layout (bytes), ~2.5 MB total
    char* base = (char*)d_ws;
    int*            idx     = (int*)(base + 0);                     // 1,048,576
    float*          out_pre = (float*)(base + 1048576);             // 1,048,576
    unsigned int*   pf16    = (unsigned int*)(base + 2097152);      //    262,144
    unsigned int*   W3f     = (unsigned int*)(base + 2359296);      //     33,792
    unsigned int*   W2f     = (unsigned int*)(base + 2393088);      //      2,048
    float*          b2p     = (float*)(base + 2395136);             //        128
    float*          st      = (float*)(base + 2395264);             //      4,608
    float4*         xs4g    = (float4*)(base + 2399872);            //    131,072
    // st floats: s1s[512] | q1s[512] | s2[32] | q2[32] | s3[32] | q3[32]
    float *s1s=st, *q1s=st+512, *s2=st+1024, *q2=st+1056, *s3=st+1088, *q3=st+1120;

    hipLaunchKernelGGL(k_prep0,   dim3(32),      dim3(256), 0, stream, xyz, xs4g, st);
    hipLaunchKernelGGL(k_knn,     dim3(B_*N_/4), dim3(256), 0, stream, xs4g, W1, b1, idx, s1s, q1s);
    hipLaunchKernelGGL(k_prep2,   dim3(260),     dim3(256), 0, stream, points, s1s, q1s, g1, be1, W2, b2,
                       pf16, W2f, b2p);
    hipLaunchKernelGGL(k_h2stats, dim3(R_/256),  dim3(256), 0, stream, xs4g, idx, W1, b1,
                       (const uint4*)W2f, b2p, s2, q2);
    hipLaunchKernelGGL(k_prep3,   dim3(33),      dim3(256), 0, stream, W3, b3, s2, q2, g2, be2, W3f);
    hipLaunchKernelGGL(k_out,     dim3(R_/256),  dim3(256), 0, stream, xs4g, idx, W1, b1,
                       (const uint4*)W2f, b2p, pf16, (const uint4*)W3f, out_pre, s3, q3);
    hipLaunchKernelGGL(k_bn,      dim3(B_*N_*COUT_/256), dim3(256), 0, stream, out_pre, s3, q3, gbn, bbn, out);
}

// Round 9
// 172.323 us; speedup vs baseline: 2.7756x; 1.0470x over previous
//
#include <hip/hip_runtime.h>

#define B_ 4
#define N_ 2048
#define K_ 32
#define CIN_ 16
#define COUT_ 32
#define H_ 32
#define R_ (B_*N_*K_)      // 262144 rows through the weight-net
#define EPS_ 1e-5f
#define INVR_ (1.0f/(float)R_)
#define INVBN_ (1.0f/(float)(B_*N_))
#define LISTCAP 160
#define NSH 16             // stat shadows

typedef __attribute__((ext_vector_type(8)))  _Float16 f16x8;
typedef __attribute__((ext_vector_type(2)))  __fp16   hw16x2;   // builtin cvt_pkrtz return type
typedef __attribute__((ext_vector_type(2)))  _Float16 f16x2;
typedef __attribute__((ext_vector_type(16))) float    f32x16;

__device__ __forceinline__ float dot3f(float ax,float ay,float az,float bx,float by,float bz){
    return fmaf(az,bz, fmaf(ay,by, ax*bx));
}
__device__ __forceinline__ unsigned int pk2(float a, float b){   // packed f16 pair (RTZ)
    union { hw16x2 v; unsigned int u; } c;
    c.v = __builtin_amdgcn_cvt_pkrtz(a, b);
    return c.u;
}
__device__ __forceinline__ unsigned int pkmul(unsigned int a, unsigned int b){  // v_pk_mul_f16
    union { unsigned int u; f16x2 v; } x, y, r;
    x.u = a; y.u = b; r.v = x.v * y.v; return r.u;
}
// sum of NSH shadow accumulators
__device__ __forceinline__ float shsum(const float* __restrict__ p, int k){
    float s = 0.f;
    #pragma unroll
    for (int i = 0; i < NSH; ++i) s += p[i*32 + k];
    return s;
}

// ---- prep0: xs4g[b*N+n] = (x,y,z,|p|^2); zero stats ----
__global__ __launch_bounds__(256) void k_prep0(const float* __restrict__ xyz, float4* __restrict__ xs4g,
                                               float* __restrict__ st){
    int i = blockIdx.x*256 + threadIdx.x;      // 32 blocks x 256 = 8192
    float x = xyz[3*i], y = xyz[3*i+1], z = xyz[3*i+2];
    xs4g[i] = make_float4(x, y, z, dot3f(x,y,z,x,y,z));
    if (blockIdx.x == 0){
        for (int j = threadIdx.x; j < 1152; j += 256) st[j] = 0.f;
    }
}

// ---------------- KNN: 1 wave/query, wave-autonomous, SINGLE-PASS linear-bucket histogram ----------------
// bucket = top-9 bits of mantissa of (d^2 + 1.0f): 512 linear-ish buckets (width 1/256 in d^2 for
// d^2<1) -> threshold bucket holds ~K+7 -> no refine pass. Rank-select on exact (bits(d),idx) keys
// keeps JAX top_k semantics. d>=0 so raw float bits order correctly (no sign flip needed).
__global__ __launch_bounds__(256,8) void k_knn(const float4* __restrict__ xs4g,
                                               const float* __restrict__ W1, const float* __restrict__ b1,
                                               int* __restrict__ idx_out,
                                               float* __restrict__ s1sh, float* __restrict__ q1sh){
    __shared__ unsigned int hist[4][512][2];          // 16 KB: per-wave 512 buckets x2 replicas
    __shared__ unsigned long long lst[4][LISTCAP];    // 5 KB
    __shared__ int kidx[4][K_];                       // 0.5 KB

    const int tid  = threadIdx.x;
    const int w    = tid >> 6;
    const int lane = tid & 63;
    const int half = lane >> 5;
    const int b    = blockIdx.x >> 9;
    const int q    = ((blockIdx.x & 511) << 2) + w;
    const int bN   = b * N_;
    unsigned int* hw = &hist[w][0][0];

    const uint4 z4 = make_uint4(0,0,0,0);
    uint4* h4 = (uint4*)hw;                           // 256 uint4 per wave
    #pragma unroll
    for (int i = 0; i < 4; ++i) h4[i*64 + lane] = z4;

    const float4 qp = xs4g[bN + q];
    const float qx = qp.x, qy = qp.y, qz = qp.z, sqq = qp.w;

    // pass 1: 32 candidates/lane, cache d-bits, linear histogram
    unsigned int fv[32];
    #pragma unroll
    for (int j = 0; j < 32; ++j){
        int c = j*64 + lane;
        float4 pt = xs4g[bN + c];
        float d = fmaf(-2.0f, dot3f(qx,qy,qz, pt.x,pt.y,pt.z), sqq) + pt.w;
        fv[j] = __float_as_uint(d);
        unsigned int u1 = __float_as_uint(d + 1.0f);
        unsigned int key = (u1 <= 0x3F800000u) ? 0u : ((u1 - 0x3F800000u) >> 15);
        key = key > 511u ? 511u : key;
        atomicAdd(&hw[key*2 + (lane & 1)], 1u);
    }

    // select: smallest bucket with cumulative >= K (lane covers 8 buckets)
    unsigned int g[8];
    #pragma unroll
    for (int t = 0; t < 4; ++t){
        uint4 h = ((const uint4*)hw)[lane*4 + t];
        g[2*t]   = h.x + h.y;
        g[2*t+1] = h.z + h.w;
    }
    unsigned int gs = 0;
    #pragma unroll
    for (int t = 0; t < 8; ++t) gs += g[t];
    unsigned int cum = gs;
    #pragma unroll
    for (int off = 1; off < 64; off <<= 1){
        unsigned int v = __shfl_up(cum, off);
        if (lane >= off) cum += v;
    }
    unsigned long long bal = __ballot(cum >= (unsigned)K_);
    int L = __ffsll(bal) - 1;
    unsigned int run = __shfl(cum, L) - __shfl(gs, L);
    int Bsel = 8*L + 7;
    {
        unsigned int c = run; bool fnd = false;
        #pragma unroll
        for (int t = 0; t < 8; ++t){
            unsigned int ht = __shfl(g[t], L, 64);
            if (!fnd && c + ht >= (unsigned)K_){ Bsel = 8*L + t; fnd = true; }
            c += ht;
        }
    }
    const float Tedge = __uint_as_float(0x3F800000u + ((unsigned)(Bsel + 1) << 15));
    const bool allin = (Bsel == 511);

    // pass 2: ballot-compaction of survivors (f1 < Tedge <=> bucket <= Bsel)
    const unsigned long long mlt = (lane == 63) ? ~0ull >> 1 : (1ull << lane) - 1ull;
    unsigned int cnt = 0;
    #pragma unroll
    for (int j = 0; j < 32; ++j){
        float f1 = __uint_as_float(fv[j]) + 1.0f;
        bool surv = (f1 < Tedge) || allin;
        unsigned long long sb = __ballot(surv);
        unsigned int pos = cnt + (unsigned int)__popcll(sb & mlt);
        if (surv && pos < (unsigned)LISTCAP)
            lst[w][pos] = ((unsigned long long)fv[j] << 32) | (unsigned int)(j*64 + lane);
        cnt += (unsigned int)__popcll(sb);
    }
    int m = (int)cnt; if (m > LISTCAP) m = LISTCAP;

    // rank-select (keys unique: idx in low bits) -> exact top_k tie-break
    int* outp = idx_out + ((size_t)bN + q) * K_;
    for (int i = lane; i < m; i += 64){
        unsigned long long my = lst[w][i];
        int rank = 0;
        for (int jj = 0; jj < m; ++jj)
            rank += (lst[w][jj] < my) ? 1 : 0;
        if (rank < K_){
            int id = (int)(unsigned int)(my & 0xFFFFFFFFull);
            outp[rank] = id;
            kidx[w][rank] = id;
        }
    }

    // fused h1 stats: ch = lane&31; halves split the 32 neighbors (16 each)
    {
        const int ch = lane & 31;
        float w1a = W1[ch], w1b = W1[H_+ch], w1c = W1[2*H_+ch], b1c = b1[ch];
        float s = 0.f, qq = 0.f;
        #pragma unroll
        for (int r = 0; r < 16; ++r){
            int idr = kidx[w][half*16 + r];            // wave-uniform LDS broadcast
            float4 pn = xs4g[bN + idr];
            float rx = pn.x - qx, ry = pn.y - qy, rz = pn.z - qz;
            float h = fmaxf(fmaf(rx, w1a, fmaf(ry, w1b, fmaf(rz, w1c, b1c))), 0.0f);
            s += h; qq = fmaf(h, h, qq);
        }
        s  += __shfl_xor(s, 32, 64);
        qq += __shfl_xor(qq, 32, 64);
        if (lane < 32){
            int sh = (blockIdx.x & (NSH-1)) * 32 + ch;
            atomicAdd(&s1sh[sh], s);
            atomicAdd(&q1sh[sh], qq);
        }
    }
}

// ---------------- h1 (raw) from xs4g ----------------
__device__ __forceinline__ void compute_h1v(const float4* __restrict__ xs4g, const int* __restrict__ idx, int r,
                                            const float* __restrict__ W1, const float* __restrict__ b1, float* h1){
    int b = r >> 16;
    int n = (r >> 5) & (N_-1);
    int id = idx[r];
    float4 pc = xs4g[b*N_ + n];
    float4 pn = xs4g[b*N_ + id];
    float rx = pn.x - pc.x, ry = pn.y - pc.y, rz = pn.z - pc.z;
    #pragma unroll
    for (int j = 0; j < H_; ++j){
        float a = fmaf(rx, W1[j], fmaf(ry, W1[H_+j], fmaf(rz, W1[2*H_+j], b1[j])));
        h1[j] = fmaxf(a, 0.0f);
    }
}

// ---- prep2: points->f16 pairs; W2' = a1(.)W2 f16 frags; b2' = b2 + bb1@W2 (shadow-summed s1/q1) ----
__global__ __launch_bounds__(256) void k_prep2(const float* __restrict__ points,
                                               const float* __restrict__ s1s, const float* __restrict__ q1s,
                                               const float* __restrict__ g1, const float* __restrict__ be1,
                                               const float* __restrict__ W2, const float* __restrict__ b2,
                                               unsigned int* __restrict__ pf16, unsigned int* __restrict__ W2f,
                                               float* __restrict__ b2p){
    int flat = blockIdx.x*256 + threadIdx.x;
    if (flat < 65536){
        pf16[flat] = pk2(points[2*flat], points[2*flat+1]);
    } else if (flat < 66048){
        int d = flat - 65536;              // W2f dword index = (s*64+lane)*4+jj
        int jj = d & 3, lane = (d >> 2) & 63, s = d >> 8;
        int col = lane & 31;
        int k0 = s*16 + (lane >> 5)*8 + 2*jj;
        float m0 = shsum(s1s,k0)*INVR_,   v0 = shsum(q1s,k0)*INVR_   - m0*m0;
        float m1 = shsum(s1s,k0+1)*INVR_, v1 = shsum(q1s,k0+1)*INVR_ - m1*m1;
        float a0  = g1[k0]   / sqrtf(v0 + EPS_);
        float a1v = g1[k0+1] / sqrtf(v1 + EPS_);
        W2f[d] = pk2(a0*W2[k0*H_ + col], a1v*W2[(k0+1)*H_ + col]);
    } else if (flat < 66080){
        int col = flat - 66048;
        float acc = b2[col];
        #pragma unroll 4
        for (int h = 0; h < H_; ++h){
            float mm = shsum(s1s,h)*INVR_, vv = shsum(q1s,h)*INVR_ - mm*mm;
            float aa = g1[h] / sqrtf(vv + EPS_);
            float bb = fmaf(-aa, mm, be1[h]);
            acc = fmaf(bb, W2[h*H_ + col], acc);
        }
        b2p[col] = acc;
    }
}

// ---- k_h2stats: h1 -> layer2 MFMA (C[row][ch]) -> relu -> per-channel stats ONLY (no h2 store) ----
__global__ __launch_bounds__(256,4) void k_h2stats(const float4* __restrict__ xs4g, const int* __restrict__ idx,
                                                   const float* __restrict__ W1, const float* __restrict__ b1,
                                                   const uint4* __restrict__ W2f, const float* __restrict__ b2p,
                                                   float* gsum, float* gsq){
    __shared__ float redS[H_], redQ[H_];
    const int tid = threadIdx.x, lane = tid & 63, w = tid >> 6;
    const int half = lane >> 5, m = lane & 31;
    if (tid < H_){ redS[tid] = 0.f; redQ[tid] = 0.f; }
    __syncthreads();

    int r = blockIdx.x*256 + tid;
    float h1[H_];
    compute_h1v(xs4g, idx, r, W1, b1, h1);
    unsigned int h1p[16];
    #pragma unroll
    for (int i = 0; i < 16; ++i) h1p[i] = pk2(h1[2*i], h1[2*i+1]);

    union { uint4 u4; f16x8 v; } Bf0, Bf1;
    Bf0.u4 = W2f[lane];
    Bf1.u4 = W2f[64 + lane];
    float b2c = b2p[m];

    float s = 0.f, q = 0.f;
    #pragma unroll
    for (int t = 0; t < 2; ++t){
        const int src = t*32 + m;
        union { unsigned int u[4]; f16x8 v; } a0, a1f;
        #pragma unroll
        for (int jj = 0; jj < 4; ++jj){
            unsigned int lo = __shfl(h1p[jj],     src, 64);
            unsigned int hi = __shfl(h1p[4 + jj], src, 64);
            a0.u[jj] = half ? hi : lo;
        }
        #pragma unroll
        for (int jj = 0; jj < 4; ++jj){
            unsigned int lo = __shfl(h1p[8 + jj],  src, 64);
            unsigned int hi = __shfl(h1p[12 + jj], src, 64);
            a1f.u[jj] = half ? hi : lo;
        }
        f32x16 acc;
        #pragma unroll
        for (int i = 0; i < 16; ++i) acc[i] = b2c;
        acc = __builtin_amdgcn_mfma_f32_32x32x16_f16(a0.v,  Bf0.v, acc, 0, 0, 0);
        acc = __builtin_amdgcn_mfma_f32_32x32x16_f16(a1f.v, Bf1.v, acc, 0, 0, 0);
        #pragma unroll
        for (int i = 0; i < 16; ++i){
            float v = fmaxf(acc[i], 0.0f);
            s += v; q = fmaf(v, v, q);
        }
    }
    s += __shfl_xor(s, 32, 64);
    q += __shfl_xor(q, 32, 64);
    if (lane < 32){ atomicAdd(&redS[m], s); atomicAdd(&redQ[m], q); }
    __syncthreads();
    if (tid < H_){ atomicAdd(&gsum[tid], redS[tid]); atomicAdd(&gsq[tid], redQ[tid]); }
}

// ---- prep3: W3'' = aa2(.)W3 (+ b3' bias row at step 32) -> f16 B-frags for K=528 ----
__global__ __launch_bounds__(256) void k_prep3(const float* __restrict__ W3, const float* __restrict__ b3,
                                               const float* __restrict__ s2, const float* __restrict__ q2,
                                               const float* __restrict__ g2, const float* __restrict__ be2,
                                               unsigned int* __restrict__ W3f){
    int d = blockIdx.x*256 + threadIdx.x;     // 33*256 = 8448 dwords
    int jj = d & 3, lane = (d >> 2) & 63, step = d >> 8;
    int col = lane & 31;
    int off = (lane >> 5)*8 + 2*jj;
    float v0, v1;
    if (step < 32){
        int h = step, c0 = off;
        float mm = s2[h]*INVR_, vv = q2[h]*INVR_ - mm*mm;
        float aa = g2[h] / sqrtf(vv + EPS_);
        v0 = aa * W3[h*512 + c0*COUT_ + col];
        v1 = aa * W3[h*512 + (c0+1)*COUT_ + col];
    } else {
        int c0 = off;
        v0 = b3[c0*COUT_ + col]; v1 = b3[(c0+1)*COUT_ + col];
        #pragma unroll 4
        for (int h = 0; h < H_; ++h){
            float mm = s2[h]*INVR_, vv = q2[h]*INVR_ - mm*mm;
            float aa = g2[h] / sqrtf(vv + EPS_);
            float bb = fmaf(-aa, mm, be2[h]);
            v0 = fmaf(bb, W3[h*512 + c0*COUT_ + col], v0);
            v1 = fmaf(bb, W3[h*512 + (c0+1)*COUT_ + col], v1);
        }
    }
    W3f[d] = pk2(v0, v1);
}

// ---- k_out (FUSED): h1 -> layer2 MFMA swapped (C[ch][row]) -> h2 in regs -> layer3 MFMA -> max ----
// W3f staged in LDS: K-loop B-frags are ds_read_b128 (16B/lane, conflict-free) instead of L2 hits.
__global__ __launch_bounds__(256,3) void k_out(const float4* __restrict__ xs4g, const int* __restrict__ idx,
                                               const float* __restrict__ W1, const float* __restrict__ b1,
                                               const uint4* __restrict__ W2f, const float* __restrict__ b2p,
                                               const unsigned int* __restrict__ pf16,
                                               const uint4* __restrict__ W3f,
                                               float* __restrict__ out_pre, float* gsum, float* gsq){
    __shared__ uint4 Wls[2112];                      // 33 KB: W3f fragments
    __shared__ float redS[COUT_], redQ[COUT_];
    const int tid = threadIdx.x, lane = tid & 63, w = tid >> 6;
    const int half = lane >> 5, m = lane & 31;
    for (int i = tid; i < 2112; i += 256) Wls[i] = W3f[i];
    if (tid < COUT_){ redS[tid] = 0.f; redQ[tid] = 0.f; }
    __syncthreads();

    const int rB = blockIdx.x*256 + w*64;
    int r = blockIdx.x*256 + tid;

    float h1[H_];
    compute_h1v(xs4g, idx, r, W1, b1, h1);
    unsigned int h1p[16];
    #pragma unroll
    for (int i = 0; i < 16; ++i) h1p[i] = pk2(h1[2*i], h1[2*i+1]);

    union { uint4 u4; f16x8 v; } A0, A1;     // W2'^T A-frags (same bits as W2f)
    A0.u4 = W2f[lane];
    A1.u4 = W2f[64 + lane];
    float b2v[16];                            // bias per C-reg: ch = (i&3)+8*(i>>2)+4*half
    #pragma unroll
    for (int i = 0; i < 16; ++i) b2v[i] = b2p[(i&3) + 8*(i>>2) + 4*half];

    #pragma unroll
    for (int t = 0; t < 2; ++t){
        const int src = t*32 + m;
        // B-frags = h1 of data-row t*32+m
        union { unsigned int u[4]; f16x8 v; } B0f, B1f;
        #pragma unroll
        for (int jj = 0; jj < 4; ++jj){
            unsigned int lo = __shfl(h1p[jj],     src, 64);
            unsigned int hi = __shfl(h1p[4 + jj], src, 64);
            B0f.u[jj] = half ? hi : lo;
        }
        #pragma unroll
        for (int jj = 0; jj < 4; ++jj){
            unsigned int lo = __shfl(h1p[8 + jj],  src, 64);
            unsigned int hi = __shfl(h1p[12 + jj], src, 64);
            B1f.u[jj] = half ? hi : lo;
        }
        f32x16 c2;
        #pragma unroll
        for (int i = 0; i < 16; ++i) c2[i] = b2v[i];
        c2 = __builtin_amdgcn_mfma_f32_32x32x16_f16(A0.v, B0f.v, c2, 0, 0, 0);
        c2 = __builtin_amdgcn_mfma_f32_32x32x16_f16(A1.v, B1f.v, c2, 0, 0, 0);

        // relu + pack + half-exchange -> h2p[16] = row (t*32+m)'s 32 channels, f16-packed
        unsigned int h2p[16];
        #pragma unroll
        for (int p = 0; p < 8; ++p){
            float v0 = fmaxf(c2[2*p],   0.0f);
            float v1 = fmaxf(c2[2*p+1], 0.0f);
            unsigned int ow = pk2(v0, v1);
            unsigned int ot = __shfl_xor(ow, 32, 64);
            int a = p >> 1, bb = p & 1;
            h2p[4*a + 2*half     + bb] = ow;
            h2p[4*a + 2*(1-half) + bb] = ot;
        }

        // gp for row t*32+m
        int row = rB + t*32 + m;
        int bb_ = row >> 16;
        int idr = idx[row];
        const uint4* gpp = (const uint4*)(pf16 + ((size_t)bb_*N_ + idr)*8);
        uint4 ga = gpp[0], gb = gpp[1];
        unsigned int gsel[4];
        gsel[0] = half ? gb.x : ga.x;
        gsel[1] = half ? gb.y : ga.y;
        gsel[2] = half ? gb.z : ga.z;
        gsel[3] = half ? gb.w : ga.w;

        f32x16 acc;
        #pragma unroll
        for (int i = 0; i < 16; ++i) acc[i] = 0.f;
        #pragma unroll
        for (int kb = 0; kb < 32; ++kb){
            unsigned int hr = h2p[kb >> 1];
            unsigned int hd = __builtin_amdgcn_perm(hr, hr, (kb & 1) ? 0x03020302u : 0x01000100u);
            union { unsigned int u[4]; f16x8 v; } af;
            #pragma unroll
            for (int jj = 0; jj < 4; ++jj) af.u[jj] = pkmul(hd, gsel[jj]);
            union { uint4 u4; f16x8 v; } bf; bf.u4 = Wls[kb*64 + lane];
            acc = __builtin_amdgcn_mfma_f32_32x32x16_f16(af.v, bf.v, acc, 0, 0, 0);
        }
        {   // bias step: A = gp, B = b3'
            union { unsigned int u[4]; f16x8 v; } af;
            #pragma unroll
            for (int jj = 0; jj < 4; ++jj) af.u[jj] = gsel[jj];
            union { uint4 u4; f16x8 v; } bf; bf.u4 = Wls[32*64 + lane];
            acc = __builtin_amdgcn_mfma_f32_32x32x16_f16(af.v, bf.v, acc, 0, 0, 0);
        }

        float v = acc[0];
        #pragma unroll
        for (int i = 1; i < 16; ++i) v = fmaxf(v, acc[i]);
        v = fmaxf(v, __shfl_xor(v, 32, 64));
        if (lane < 32){
            int g = blockIdx.x*8 + w*2 + t;
            out_pre[(size_t)g*COUT_ + m] = v;
            atomicAdd(&redS[m], v);
            atomicAdd(&redQ[m], v*v);
        }
    }
    __syncthreads();
    if (tid < COUT_){ atomicAdd(&gsum[tid], redS[tid]); atomicAdd(&gsq[tid], redQ[tid]); }
}

__global__ __launch_bounds__(256) void k_bn(const float* __restrict__ out_pre,
                                            const float* __restrict__ s3, const float* __restrict__ q3,
                                            const float* __restrict__ gbn, const float* __restrict__ bbn,
                                            float* __restrict__ out){
    int i = blockIdx.x*256 + threadIdx.x;
    int o = i & (COUT_-1);
    float mm = s3[o] * INVBN_;
    float vv = q3[o] * INVBN_ - mm*mm;
    float aa = gbn[o] / sqrtf(vv + EPS_);
    out[i] = fmaf(aa, out_pre[i], fmaf(-aa, mm, bbn[o]));
}

extern "C" void kernel_launch(void* const* d_in, const int* in_sizes, int n_in,
                              void* d_out, int out_size, void* d_ws, size_t ws_size,
                              hipStream_t stream){
    const float* xyz    = (const float*)d_in[0];
    const float* points = (const float*)d_in[1];
    const float* W1  = (const float*)d_in[2];
    const float* b1  = (const float*)d_in[3];
    const float* g1  = (const float*)d_in[4];
    const float* be1 = (const float*)d_in[5];
    const float* W2  = (const float*)d_in[6];
    const float* b2  = (const float*)d_in[7];
    const float* g2  = (const float*)d_in[8];
    const float* be2 = (const float*)d_in[9];
    const float* W3  = (const float*)d_in[10];
    const float* b3  = (const float*)d_in[11];
    const float* gbn = (const float*)d_in[12];
    const float* bbn = (const float*)d_in[13];
    float* out = (float*)d_out;

    // ws layout (bytes), ~2.5 MB total
    char* base = (char*)d_ws;
    int*            idx     = (int*)(base + 0);                     // 1,048,576
    float*          out_pre = (float*)(base + 1048576);             // 1,048,576
    unsigned int*   pf16    = (unsigned int*)(base + 2097152);      //    262,144
    unsigned int*   W3f     = (unsigned int*)(base + 2359296);      //     33,792
    unsigned int*   W2f     = (unsigned int*)(base + 2393088);      //      2,048
    float*          b2p     = (float*)(base + 2395136);             //        128
    float*          st      = (float*)(base + 2395264);             //      4,608
    float4*         xs4g    = (float4*)(base + 2399872);            //    131,072
    // st floats: s1s[512] | q1s[512] | s2[32] | q2[32] | s3[32] | q3[32]
    float *s1s=st, *q1s=st+512, *s2=st+1024, *q2=st+1056, *s3=st+1088, *q3=st+1120;

    hipLaunchKernelGGL(k_prep0,   dim3(32),      dim3(256), 0, stream, xyz, xs4g, st);
    hipLaunchKernelGGL(k_knn,     dim3(B_*N_/4), dim3(256), 0, stream, xs4g, W1, b1, idx, s1s, q1s);
    hipLaunchKernelGGL(k_prep2,   dim3(260),     dim3(256), 0, stream, points, s1s, q1s, g1, be1, W2, b2,
                       pf16, W2f, b2p);
    hipLaunchKernelGGL(k_h2stats, dim3(R_/256),  dim3(256), 0, stream, xs4g, idx, W1, b1,
                       (const uint4*)W2f, b2p, s2, q2);
    hipLaunchKernelGGL(k_prep3,   dim3(33),      dim3(256), 0, stream, W3, b3, s2, q2, g2, be2, W3f);
    hipLaunchKernelGGL(k_out,     dim3(R_/256),  dim3(256), 0, stream, xs4g, idx, W1, b1,
                       (const uint4*)W2f, b2p, pf16, (const uint4*)W3f, out_pre, s3, q3);
    hipLaunchKernelGGL(k_bn,      dim3(B_*N_*COUT_/256), dim3(256), 0, stream, out_pre, s3, q3, gbn, bbn, out);
}